// Round 3
// baseline (281.185 us; speedup 1.0000x reference)
//
#include <hip/hip_runtime.h>

#define TB 256
#define NA_G (32 * 12 * 1024)   // 16B-groups in A tiles
#define NB_G (64 * 12 * 1024)   // 16B-groups in B tiles

typedef __bf16 bf16x8 __attribute__((ext_vector_type(8)));
typedef float f32x4 __attribute__((ext_vector_type(4)));
typedef unsigned long long ull;

__device__ __forceinline__ unsigned pack2bf(float a, float b) {
  unsigned ua = __float_as_uint(a), ub = __float_as_uint(b);
  ua = (ua + 0x7fffu + ((ua >> 16) & 1u)) >> 16;   // RNE f32->bf16
  ub = (ub + 0x7fffu + ((ub >> 16) & 1u)) >> 16;
  return ua | (ub << 16);
}

__device__ __forceinline__ void gll16(const void* g, void* l) {
  __builtin_amdgcn_global_load_lds(
      (const __attribute__((address_space(1))) unsigned*)g,
      (__attribute__((address_space(3))) unsigned*)l, 16, 0, 0);
}

// Pre-convert f32 -> bf16 into swizzled 128x64 tiles (LDS-image layout).
__global__ __launch_bounds__(256) void convert_pack(
    const float* __restrict__ q, const float* __restrict__ p,
    unsigned char* __restrict__ qt, unsigned char* __restrict__ pt) {
  int g = blockIdx.x * 256 + threadIdx.x;
  const float* src;
  unsigned char* dst;
  if (g < NA_G) { src = q; dst = qt; }
  else { g -= NA_G; src = p; dst = pt; }
  int tile = g >> 10;
  int o = (g & 1023) * 16;                 // byte offset in 16KB tile
  int row = o >> 7;
  int colb = (o & 127) ^ ((row & 7) << 4); // inverse of XOR swizzle
  int rb = tile / 12, kt = tile - rb * 12;
  const float* s = src + ((size_t)(rb * 128 + row)) * 768 + kt * 64 + (colb >> 1);
  float4 a = ((const float4*)s)[0];
  float4 b = ((const float4*)s)[1];
  uint4 w;
  w.x = pack2bf(a.x, a.y); w.y = pack2bf(a.z, a.w);
  w.z = pack2bf(b.x, b.y); w.w = pack2bf(b.z, b.w);
  *(uint4*)(dst + (size_t)tile * 16384 + o) = w;
}

// rank-search a 256-bin wave-private histogram; all lanes get (selB,Rin,cnt)
__device__ __forceinline__ void scanHist(const unsigned* Hw, int lane, int R,
                                         bool fromTop, int& selB, int& Rin, int& cnt) {
  uint4 h = ((const uint4*)Hw)[lane];
  unsigned l0 = h.x, l1 = h.y, l2 = h.z, l3 = h.w;
  unsigned lsum = l0 + l1 + l2 + l3;
  unsigned run = lsum;
  if (fromTop) {
    #pragma unroll
    for (int off = 1; off < 64; off <<= 1) {
      unsigned o = __shfl_down(run, off);
      if (lane + off < 64) run += o;
    }
  } else {
    #pragma unroll
    for (int off = 1; off < 64; off <<= 1) {
      unsigned o = __shfl_up(run, off);
      if (lane >= off) run += o;
    }
  }
  unsigned excl = run - lsum;
  bool found = ((unsigned)R > excl) && ((unsigned)R <= run);
  int sb = 0, ri = 0, cc = 0;
  if (found) {
    unsigned a = excl;
    if (fromTop) {
      if ((unsigned)R <= a + l3) { sb = 3; ri = R - (int)a; cc = (int)l3; }
      else { a += l3;
      if ((unsigned)R <= a + l2) { sb = 2; ri = R - (int)a; cc = (int)l2; }
      else { a += l2;
      if ((unsigned)R <= a + l1) { sb = 1; ri = R - (int)a; cc = (int)l1; }
      else { a += l1; sb = 0; ri = R - (int)a; cc = (int)l0; } } }
    } else {
      if ((unsigned)R <= a + l0) { sb = 0; ri = R - (int)a; cc = (int)l0; }
      else { a += l0;
      if ((unsigned)R <= a + l1) { sb = 1; ri = R - (int)a; cc = (int)l1; }
      else { a += l1;
      if ((unsigned)R <= a + l2) { sb = 2; ri = R - (int)a; cc = (int)l2; }
      else { a += l2; sb = 3; ri = R - (int)a; cc = (int)l3; } } }
    }
    sb += lane * 4;
  }
  ull fm = __ballot(found);
  int src = fm ? (int)__builtin_ctzll(fm) : 0;   // FIX: was ctzll(fm|1) == always 0
  selB = __shfl(sb, src);
  Rin = __shfl(ri, src);
  cnt = __shfl(cc, src);
}

template <int PATH>
__global__ __launch_bounds__(TB) void dpr_fused(
    const float* __restrict__ q_emb, const float* __restrict__ p_emb,
    const void* __restrict__ qmr, const void* __restrict__ pmr,
    const float* __restrict__ alpha_raw, const float* __restrict__ beta_raw,
    const unsigned char* __restrict__ qt, const unsigned char* __restrict__ pt,
    float* __restrict__ out) {
  const int H = 768;
  __shared__ __align__(16) unsigned short Al[128 * 64];
  __shared__ __align__(16) unsigned short Bl[128 * 64];
  __shared__ unsigned hist[4 * 256];
  __shared__ float list4[4 * 64];
  __shared__ unsigned lcnt4[4];

  const int tid = threadIdx.x, lane = tid & 63, wid = tid >> 6;
  const int bid = blockIdx.x, blockB = bid >> 6, blockP = bid & 63;
  const int lr = lane & 15, lg = lane >> 4;
  const int db = wid >> 1, dp = wid & 1;

  // ---- per-wave masks (dtype sniffed) ----
  bool m32 = true;
  {
    const unsigned* qm32 = (const unsigned*)qmr;
    #pragma unroll
    for (int i = 0; i < 8; ++i) m32 = m32 && (qm32[i] <= 1u);
  }
  int qrow = (blockB * 2 + db) * 64 + lane;
  int pcolg = (blockP * 2 + dp) * 64 + lane;
  bool qvb = m32 ? (((const int*)qmr)[qrow] != 0) : (((const unsigned char*)qmr)[qrow] != 0);
  bool pvb = m32 ? (((const int*)pmr)[pcolg] != 0) : (((const unsigned char*)pmr)[pcolg] != 0);
  ull qb = __ballot(qvb);
  ull pb = __ballot(pvb);
  const int n_pair = __popcll(qb) * __popcll(pb);

  // ---- GEMM: 128x128 block tile, each wave owns one 64x64 pair ----
  f32x4 acc[4][4];
  #pragma unroll
  for (int m = 0; m < 4; ++m)
    #pragma unroll
    for (int n = 0; n < 4; ++n)
      acc[m][n] = f32x4{0.f, 0.f, 0.f, 0.f};

  const float* Abase = q_emb + (size_t)(blockB * 128) * H;
  const float* Bbase = p_emb + (size_t)(blockP * 128) * H;

  for (int kt = 0; kt < 12; ++kt) {
    if (PATH == 0) {
      const int k0 = kt * 64;
      #pragma unroll
      for (int it = 0; it < 4; ++it) {
        int g = tid + 256 * it;
        int row = g >> 3;
        int col = (g & 7) * 8;
        int off = (row * 128 + col * 2) ^ ((row & 7) << 4);
        const float4* sA = (const float4*)(Abase + (size_t)row * H + k0 + col);
        float4 a0 = sA[0], a1 = sA[1];
        uint4 w;
        w.x = pack2bf(a0.x, a0.y); w.y = pack2bf(a0.z, a0.w);
        w.z = pack2bf(a1.x, a1.y); w.w = pack2bf(a1.z, a1.w);
        *(uint4*)((char*)Al + off) = w;
        const float4* sB = (const float4*)(Bbase + (size_t)row * H + k0 + col);
        float4 b0 = sB[0], b1 = sB[1];
        w.x = pack2bf(b0.x, b0.y); w.y = pack2bf(b0.z, b0.w);
        w.z = pack2bf(b1.x, b1.y); w.w = pack2bf(b1.z, b1.w);
        *(uint4*)((char*)Bl + off) = w;
      }
    } else {
      const unsigned char* qtile = qt + ((size_t)(blockB * 12 + kt)) * 16384;
      const unsigned char* ptile = pt + ((size_t)(blockP * 12 + kt)) * 16384;
      #pragma unroll
      for (int c2 = 0; c2 < 4; ++c2) {
        int chunk = wid * 4 + c2;
        gll16(qtile + chunk * 1024 + lane * 16, (char*)Al + chunk * 1024);
        gll16(ptile + chunk * 1024 + lane * 16, (char*)Bl + chunk * 1024);
      }
    }
    __syncthreads();
    #pragma unroll
    for (int ks = 0; ks < 2; ++ks) {
      bf16x8 af[4], bfr[4];
      #pragma unroll
      for (int m = 0; m < 4; ++m) {
        int row = db * 64 + m * 16 + lr;
        int off = (row * 128 + ks * 64 + lg * 16) ^ ((row & 7) << 4);
        af[m] = *(const bf16x8*)((const char*)Al + off);
      }
      #pragma unroll
      for (int n = 0; n < 4; ++n) {
        int row = dp * 64 + n * 16 + lr;
        int off = (row * 128 + ks * 64 + lg * 16) ^ ((row & 7) << 4);
        bfr[n] = *(const bf16x8*)((const char*)Bl + off);
      }
      #pragma unroll
      for (int m = 0; m < 4; ++m)
        #pragma unroll
        for (int n = 0; n < 4; ++n)
          acc[m][n] = __builtin_amdgcn_mfma_f32_16x16x32_bf16(af[m], bfr[n], acc[m][n], 0, 0, 0);
    }
    __syncthreads();
  }

  // ---- wave-parallel selection (no block barriers from here on) ----
  const int outIdx = (blockB * 2 + db) * 128 + (blockP * 2 + dp);
  if (n_pair == 0) {
    if (lane == 0) out[outIdx] = -1e9f;
    return;
  }

  unsigned pcb[4];
  #pragma unroll
  for (int n = 0; n < 4; ++n) pcb[n] = (unsigned)((pb >> (n * 16 + lr)) & 1ull);

  // masked sum / min / max over this wave's 64 values per lane
  float tsum = 0.f, mn = INFINITY, mx = -INFINITY;
  #pragma unroll
  for (int m = 0; m < 4; ++m)
    #pragma unroll
    for (int j = 0; j < 4; ++j) {
      unsigned qbit = (unsigned)((qb >> (m * 16 + lg * 4 + j)) & 1ull);
      #pragma unroll
      for (int n = 0; n < 4; ++n) {
        bool val = (qbit & pcb[n]) != 0u;
        float x = acc[m][n][j];
        tsum += val ? x : 0.f;
        if (val) { mn = fminf(mn, x); mx = fmaxf(mx, x); }
      }
    }
  #pragma unroll
  for (int off = 1; off < 64; off <<= 1) {
    tsum += __shfl_xor(tsum, off);
    mn = fminf(mn, __shfl_xor(mn, off));
    mx = fmaxf(mx, __shfl_xor(mx, off));
  }

  int ksel = 4 * n_pair / 10; if (ksel < 1) ksel = 1;
  int lsel = 2 * n_pair / 10; if (lsel < 1) lsel = 1;

  unsigned* Hw = hist + wid * 256;
  float* listw = list4 + wid * 64;
  unsigned* lcw = lcnt4 + wid;

  // exact threshold refinement over candidates in one bin (<=64 typ.)
  auto refine = [&](ull alive, float lo, float hi, int R, int c, bool largest) -> float {
    for (int lev = 0; lev < 3 && c > 64; ++lev) {
      if (!(hi > lo)) return lo;
      ((uint4*)Hw)[lane] = uint4{0u, 0u, 0u, 0u};
      float sc = 255.0f / (hi - lo);
      #pragma unroll
      for (int m = 0; m < 4; ++m)
        #pragma unroll
        for (int n = 0; n < 4; ++n)
          #pragma unroll
          for (int j = 0; j < 4; ++j) {
            const int idx = (m * 4 + n) * 4 + j;
            if ((alive >> idx) & 1ull) {
              int b = (int)((acc[m][n][j] - lo) * sc);
              b = b < 0 ? 0 : (b > 255 ? 255 : b);
              atomicAdd(&Hw[b], 1u);
            }
          }
      int sb, ri, cc;
      scanHist(Hw, lane, R, largest, sb, ri, cc);
      ull na = 0;
      #pragma unroll
      for (int m = 0; m < 4; ++m)
        #pragma unroll
        for (int n = 0; n < 4; ++n)
          #pragma unroll
          for (int j = 0; j < 4; ++j) {
            const int idx = (m * 4 + n) * 4 + j;
            if ((alive >> idx) & 1ull) {
              int b = (int)((acc[m][n][j] - lo) * sc);
              b = b < 0 ? 0 : (b > 255 ? 255 : b);
              na |= (ull)(b == sb) << idx;
            }
          }
      alive = na; R = ri; c = cc;
      float w = (hi - lo) * (1.0f / 255.0f);
      float nlo = lo + w * (float)(sb & 255);
      hi = nlo + w; lo = nlo;
    }
    if (c > 64) return lo;  // pathological fallback (tiny bounded error)
    if (lane == 0) *lcw = 0u;
    #pragma unroll
    for (int m = 0; m < 4; ++m)
      #pragma unroll
      for (int n = 0; n < 4; ++n)
        #pragma unroll
        for (int j = 0; j < 4; ++j) {
          const int idx = (m * 4 + n) * 4 + j;
          if ((alive >> idx) & 1ull) {
            unsigned pp = atomicAdd(lcw, 1u);
            if (pp < 64u) listw[pp] = acc[m][n][j];
          }
        }
    int cc2 = c;
    if (R > cc2) R = cc2;
    float myv = (lane < cc2) ? listw[lane] : 0.0f;
    int cg = 0, ce = 0;
    for (int q2 = 0; q2 < cc2; ++q2) {
      float o = listw[q2];
      cg += largest ? (o > myv) : (o < myv);
      ce += (o == myv);
    }
    bool found = (lane < cc2) && (cg < R) && (R <= cg + ce);
    ull fm = __ballot(found);
    int srcl = fm ? (int)__builtin_ctzll(fm) : 0;  // FIX: was ctzll(fm|1) == always 0
    return __shfl(myv, srcl);
  };

  float tT, tB;
  if (!(mx > mn)) {
    tT = mn; tB = mn;   // all valid values equal
  } else {
    // level-0 histogram over all valid values (shared by top & bottom)
    ((uint4*)Hw)[lane] = uint4{0u, 0u, 0u, 0u};
    const float sc0 = 255.0f / (mx - mn);
    #pragma unroll
    for (int m = 0; m < 4; ++m)
      #pragma unroll
      for (int j = 0; j < 4; ++j) {
        unsigned qbit = (unsigned)((qb >> (m * 16 + lg * 4 + j)) & 1ull);
        #pragma unroll
        for (int n = 0; n < 4; ++n) {
          if ((qbit & pcb[n]) != 0u) {
            int b = (int)((acc[m][n][j] - mn) * sc0);
            b = b < 0 ? 0 : (b > 255 ? 255 : b);
            atomicAdd(&Hw[b], 1u);
          }
        }
      }
    int sbT, RT, cT0, sbB, RB, cB0;
    scanHist(Hw, lane, ksel, true, sbT, RT, cT0);
    scanHist(Hw, lane, lsel, false, sbB, RB, cB0);
    // restrict candidates for both selections in one pass
    ull aT = 0, aB = 0;
    #pragma unroll
    for (int m = 0; m < 4; ++m)
      #pragma unroll
      for (int j = 0; j < 4; ++j) {
        unsigned qbit = (unsigned)((qb >> (m * 16 + lg * 4 + j)) & 1ull);
        #pragma unroll
        for (int n = 0; n < 4; ++n) {
          const int idx = (m * 4 + n) * 4 + j;
          if ((qbit & pcb[n]) != 0u) {
            int b = (int)((acc[m][n][j] - mn) * sc0);
            b = b < 0 ? 0 : (b > 255 ? 255 : b);
            aT |= (ull)(b == sbT) << idx;
            aB |= (ull)(b == sbB) << idx;
          }
        }
      }
    const float w0 = (mx - mn) * (1.0f / 255.0f);
    tT = refine(aT, mn + w0 * (float)sbT, mn + w0 * (float)(sbT + 1), RT, cT0, true);
    tB = refine(aB, mn + w0 * (float)sbB, mn + w0 * (float)(sbB + 1), RB, cB0, false);
  }

  // tie-aware exact sums from thresholds
  float sT = 0.f, sB = 0.f;
  int cT = 0, cB = 0;
  #pragma unroll
  for (int m = 0; m < 4; ++m)
    #pragma unroll
    for (int j = 0; j < 4; ++j) {
      unsigned qbit = (unsigned)((qb >> (m * 16 + lg * 4 + j)) & 1ull);
      #pragma unroll
      for (int n = 0; n < 4; ++n) {
        if ((qbit & pcb[n]) != 0u) {
          float x = acc[m][n][j];
          bool gt = x > tT;
          sT += gt ? x : 0.f; cT += gt;
          bool lt = x < tB;
          sB += lt ? x : 0.f; cB += lt;
        }
      }
    }
  #pragma unroll
  for (int off = 1; off < 64; off <<= 1) {
    sT += __shfl_xor(sT, off);
    sB += __shfl_xor(sB, off);
    cT += __shfl_xor(cT, off);
    cB += __shfl_xor(cB, off);
  }

  if (lane == 0) {
    float top_sum = sT + tT * (float)(ksel - cT);
    float bot_sum = sB + tB * (float)(lsel - cB);
    float alpha = log1pf(expf(alpha_raw[0]));
    float beta = log1pf(expf(beta_raw[0]));
    float total_mean = tsum / (float)n_pair;
    float top_mean = top_sum / (float)ksel;
    float bm = fmaxf(0.0f, -(bot_sum / (float)lsel));
    out[outIdx] = total_mean + alpha * top_mean - beta * bm;
  }
}

extern "C" void kernel_launch(void* const* d_in, const int* in_sizes, int n_in,
                              void* d_out, int out_size, void* d_ws, size_t ws_size,
                              hipStream_t stream) {
  (void)in_sizes; (void)n_in; (void)out_size;
  const float* q_emb = (const float*)d_in[0];
  const float* p_emb = (const float*)d_in[1];
  const void* q_mask = d_in[2];
  const void* p_mask = d_in[3];
  const float* alpha_raw = (const float*)d_in[4];
  const float* beta_raw = (const float*)d_in[5];
  float* out = (float*)d_out;

  const size_t needWs = ((size_t)(NA_G + NB_G)) * 16;  // 18.87 MB bf16 tiles
  if (ws_size >= needWs) {
    unsigned char* qt = (unsigned char*)d_ws;
    unsigned char* pt = qt + (size_t)NA_G * 16;
    hipLaunchKernelGGL(convert_pack, dim3((NA_G + NB_G) / 256), dim3(256), 0, stream,
                       q_emb, p_emb, qt, pt);
    hipLaunchKernelGGL((dpr_fused<1>), dim3(2048), dim3(TB), 0, stream,
                       q_emb, p_emb, q_mask, p_mask, alpha_raw, beta_raw, qt, pt, out);
  } else {
    hipLaunchKernelGGL((dpr_fused<0>), dim3(2048), dim3(TB), 0, stream,
                       q_emb, p_emb, q_mask, p_mask, alpha_raw, beta_raw,
                       (const unsigned char*)nullptr, (const unsigned char*)nullptr, out);
  }
}

// Round 4
// 280.451 us; speedup vs baseline: 1.0026x; 1.0026x over previous
//
#include <hip/hip_runtime.h>

#define TB 256
#define NA_G (32 * 12 * 1024)   // 16B-groups in A tiles
#define NB_G (64 * 12 * 1024)   // 16B-groups in B tiles

typedef __bf16 bf16x8 __attribute__((ext_vector_type(8)));
typedef float f32x4 __attribute__((ext_vector_type(4)));
typedef unsigned long long ull;

__device__ __forceinline__ unsigned pack2bf(float a, float b) {
  unsigned ua = __float_as_uint(a), ub = __float_as_uint(b);
  ua = (ua + 0x7fffu + ((ua >> 16) & 1u)) >> 16;   // RNE f32->bf16
  ub = (ub + 0x7fffu + ((ub >> 16) & 1u)) >> 16;
  return ua | (ub << 16);
}

__device__ __forceinline__ void gll16(const void* g, void* l) {
  __builtin_amdgcn_global_load_lds(
      (const __attribute__((address_space(1))) unsigned*)g,
      (__attribute__((address_space(3))) unsigned*)l, 16, 0, 0);
}

// Pre-convert f32 -> bf16 into swizzled 128x64 tiles (LDS-image layout).
__global__ __launch_bounds__(256) void convert_pack(
    const float* __restrict__ q, const float* __restrict__ p,
    unsigned char* __restrict__ qt, unsigned char* __restrict__ pt) {
  int g = blockIdx.x * 256 + threadIdx.x;
  const float* src;
  unsigned char* dst;
  if (g < NA_G) { src = q; dst = qt; }
  else { g -= NA_G; src = p; dst = pt; }
  int tile = g >> 10;
  int o = (g & 1023) * 16;                 // byte offset in 16KB tile
  int row = o >> 7;
  int colb = (o & 127) ^ ((row & 7) << 4); // inverse of XOR swizzle
  int rb = tile / 12, kt = tile - rb * 12;
  const float* s = src + ((size_t)(rb * 128 + row)) * 768 + kt * 64 + (colb >> 1);
  float4 a = ((const float4*)s)[0];
  float4 b = ((const float4*)s)[1];
  uint4 w;
  w.x = pack2bf(a.x, a.y); w.y = pack2bf(a.z, a.w);
  w.z = pack2bf(b.x, b.y); w.w = pack2bf(b.z, b.w);
  *(uint4*)(dst + (size_t)tile * 16384 + o) = w;
}

// ---- hot scans: counts + value-sums, compile-time direction ----
__device__ __forceinline__ void scanTopSum(const unsigned* hC, const float* hS,
                                           int lane, int R, int& selB, int& Rin,
                                           int& cnt, float& sumAbove) {
  uint4 c4 = ((const uint4*)hC)[lane];
  float4 s4 = ((const float4*)hS)[lane];
  unsigned lc = c4.x + c4.y + c4.z + c4.w;
  float ls = s4.x + s4.y + s4.z + s4.w;
  unsigned run = lc; float runv = ls;
  #pragma unroll
  for (int off = 1; off < 64; off <<= 1) {
    unsigned o = __shfl_down(run, off);
    float ov = __shfl_down(runv, off);
    if (lane + off < 64) { run += o; runv += ov; }
  }
  unsigned above = run - lc; float vabove = runv - ls;
  bool found = ((unsigned)R > above) && ((unsigned)R <= run);
  int sb = 0, ri = 0, cc = 0; float sa = 0.f;
  if (found) {
    unsigned a = above; float va = vabove;
    if ((unsigned)R <= a + c4.w) { sb = 3; ri = R - (int)a; cc = (int)c4.w; sa = va; }
    else { a += c4.w; va += s4.w;
    if ((unsigned)R <= a + c4.z) { sb = 2; ri = R - (int)a; cc = (int)c4.z; sa = va; }
    else { a += c4.z; va += s4.z;
    if ((unsigned)R <= a + c4.y) { sb = 1; ri = R - (int)a; cc = (int)c4.y; sa = va; }
    else { a += c4.y; va += s4.y; sb = 0; ri = R - (int)a; cc = (int)c4.x; sa = va; } } }
    sb += lane * 4;
  }
  ull fm = __ballot(found);
  int src = fm ? (int)__builtin_ctzll(fm) : 0;
  selB = __shfl(sb, src); Rin = __shfl(ri, src);
  cnt = __shfl(cc, src); sumAbove = __shfl(sa, src);
}

__device__ __forceinline__ void scanBotSum(const unsigned* hC, const float* hS,
                                           int lane, int R, int& selB, int& Rin,
                                           int& cnt, float& sumBelow) {
  uint4 c4 = ((const uint4*)hC)[lane];
  float4 s4 = ((const float4*)hS)[lane];
  unsigned lc = c4.x + c4.y + c4.z + c4.w;
  float ls = s4.x + s4.y + s4.z + s4.w;
  unsigned run = lc; float runv = ls;
  #pragma unroll
  for (int off = 1; off < 64; off <<= 1) {
    unsigned o = __shfl_up(run, off);
    float ov = __shfl_up(runv, off);
    if (lane >= off) { run += o; runv += ov; }
  }
  unsigned below = run - lc; float vbelow = runv - ls;
  bool found = ((unsigned)R > below) && ((unsigned)R <= run);
  int sb = 0, ri = 0, cc = 0; float sa = 0.f;
  if (found) {
    unsigned a = below; float va = vbelow;
    if ((unsigned)R <= a + c4.x) { sb = 0; ri = R - (int)a; cc = (int)c4.x; sa = va; }
    else { a += c4.x; va += s4.x;
    if ((unsigned)R <= a + c4.y) { sb = 1; ri = R - (int)a; cc = (int)c4.y; sa = va; }
    else { a += c4.y; va += s4.y;
    if ((unsigned)R <= a + c4.z) { sb = 2; ri = R - (int)a; cc = (int)c4.z; sa = va; }
    else { a += c4.z; va += s4.z; sb = 3; ri = R - (int)a; cc = (int)c4.w; sa = va; } } }
    sb += lane * 4;
  }
  ull fm = __ballot(found);
  int src = fm ? (int)__builtin_ctzll(fm) : 0;
  selB = __shfl(sb, src); Rin = __shfl(ri, src);
  cnt = __shfl(cc, src); sumBelow = __shfl(sa, src);
}

// count-only scan, runtime direction (cold fallback path)
__device__ __forceinline__ void scanCount(const unsigned* hC, int lane, int R,
                                          bool fromTop, int& selB, int& Rin, int& cnt) {
  uint4 h = ((const uint4*)hC)[lane];
  unsigned lsum = h.x + h.y + h.z + h.w;
  unsigned run = lsum;
  if (fromTop) {
    #pragma unroll
    for (int off = 1; off < 64; off <<= 1) {
      unsigned o = __shfl_down(run, off);
      if (lane + off < 64) run += o;
    }
  } else {
    #pragma unroll
    for (int off = 1; off < 64; off <<= 1) {
      unsigned o = __shfl_up(run, off);
      if (lane >= off) run += o;
    }
  }
  unsigned excl = run - lsum;
  bool found = ((unsigned)R > excl) && ((unsigned)R <= run);
  int sb = 0, ri = 0, cc = 0;
  if (found) {
    unsigned a = excl;
    if (fromTop) {
      if ((unsigned)R <= a + h.w) { sb = 3; ri = R - (int)a; cc = (int)h.w; }
      else { a += h.w;
      if ((unsigned)R <= a + h.z) { sb = 2; ri = R - (int)a; cc = (int)h.z; }
      else { a += h.z;
      if ((unsigned)R <= a + h.y) { sb = 1; ri = R - (int)a; cc = (int)h.y; }
      else { a += h.y; sb = 0; ri = R - (int)a; cc = (int)h.x; } } }
    } else {
      if ((unsigned)R <= a + h.x) { sb = 0; ri = R - (int)a; cc = (int)h.x; }
      else { a += h.x;
      if ((unsigned)R <= a + h.y) { sb = 1; ri = R - (int)a; cc = (int)h.y; }
      else { a += h.y;
      if ((unsigned)R <= a + h.z) { sb = 2; ri = R - (int)a; cc = (int)h.z; }
      else { a += h.z; sb = 3; ri = R - (int)a; cc = (int)h.w; } } }
    }
    sb += lane * 4;
  }
  ull fm = __ballot(found);
  int src = fm ? (int)__builtin_ctzll(fm) : 0;
  selB = __shfl(sb, src); Rin = __shfl(ri, src); cnt = __shfl(cc, src);
}

// sum of top/bottom-R among list[0..c), exact & tie-safe (c<=64, R<=c)
__device__ __forceinline__ float rankSum(const float* list, int c, int R,
                                         bool largest, int lane) {
  float myv = (lane < c) ? list[lane] : 0.f;
  int cg = 0, ceb = 0;
  for (int q = 0; q < c; ++q) {
    float o = list[q];
    cg += largest ? (o > myv) : (o < myv);
    ceb += (q < lane) && (o == myv);
  }
  float s = ((lane < c) && (cg + ceb < R)) ? myv : 0.f;
  #pragma unroll
  for (int off = 1; off < 64; off <<= 1) s += __shfl_xor(s, off);
  return s;
}

// exact R-th largest/smallest among list[0..c)  (c<=64, R<=c)
__device__ __forceinline__ float rankSelect(const float* list, int c, int R,
                                            bool largest, int lane) {
  float myv = (lane < c) ? list[lane] : 0.f;
  int cg = 0, ce = 0;
  for (int q = 0; q < c; ++q) {
    float o = list[q];
    cg += largest ? (o > myv) : (o < myv);
    ce += (o == myv);
  }
  bool found = (lane < c) && (cg < R) && (R <= cg + ce);
  ull fm = __ballot(found);
  int src = fm ? (int)__builtin_ctzll(fm) : 0;
  return __shfl(myv, src);
}

template <int PATH>
__global__ __launch_bounds__(TB, 4) void dpr_fused(
    const float* __restrict__ q_emb, const float* __restrict__ p_emb,
    const void* __restrict__ qmr, const void* __restrict__ pmr,
    const float* __restrict__ alpha_raw, const float* __restrict__ beta_raw,
    const unsigned char* __restrict__ qt, const unsigned char* __restrict__ pt,
    float* __restrict__ out) {
  const int H = 768;
  __shared__ __align__(16) char arena[32768];  // GEMM: Al|Bl ; selection: hists+lists
  __shared__ unsigned lcnt[8];
  unsigned short* Al = (unsigned short*)arena;
  unsigned short* Bl = (unsigned short*)(arena + 16384);

  const int tid = threadIdx.x, lane = tid & 63, wid = tid >> 6;
  const int bid = blockIdx.x, blockB = bid >> 6, blockP = bid & 63;
  const int lr = lane & 15, lg = lane >> 4;
  const int db = wid >> 1, dp = wid & 1;

  // ---- per-wave masks (dtype sniffed) ----
  bool m32 = true;
  {
    const unsigned* qm32 = (const unsigned*)qmr;
    #pragma unroll
    for (int i = 0; i < 8; ++i) m32 = m32 && (qm32[i] <= 1u);
  }
  int qrow = (blockB * 2 + db) * 64 + lane;
  int pcolg = (blockP * 2 + dp) * 64 + lane;
  bool qvb = m32 ? (((const int*)qmr)[qrow] != 0) : (((const unsigned char*)qmr)[qrow] != 0);
  bool pvb = m32 ? (((const int*)pmr)[pcolg] != 0) : (((const unsigned char*)pmr)[pcolg] != 0);
  ull qb = __ballot(qvb);
  ull pb = __ballot(pvb);
  const int n_pair = __popcll(qb) * __popcll(pb);

  // ---- GEMM: 128x128 block tile, each wave owns one 64x64 pair ----
  f32x4 acc[4][4];
  #pragma unroll
  for (int m = 0; m < 4; ++m)
    #pragma unroll
    for (int n = 0; n < 4; ++n)
      acc[m][n] = f32x4{0.f, 0.f, 0.f, 0.f};

  const float* Abase = q_emb + (size_t)(blockB * 128) * H;
  const float* Bbase = p_emb + (size_t)(blockP * 128) * H;

  for (int kt = 0; kt < 12; ++kt) {
    if (PATH == 0) {
      const int k0 = kt * 64;
      #pragma unroll
      for (int it = 0; it < 4; ++it) {
        int g = tid + 256 * it;
        int row = g >> 3;
        int col = (g & 7) * 8;
        int off = (row * 128 + col * 2) ^ ((row & 7) << 4);
        const float4* sA = (const float4*)(Abase + (size_t)row * H + k0 + col);
        float4 a0 = sA[0], a1 = sA[1];
        uint4 w;
        w.x = pack2bf(a0.x, a0.y); w.y = pack2bf(a0.z, a0.w);
        w.z = pack2bf(a1.x, a1.y); w.w = pack2bf(a1.z, a1.w);
        *(uint4*)((char*)Al + off) = w;
        const float4* sB = (const float4*)(Bbase + (size_t)row * H + k0 + col);
        float4 b0 = sB[0], b1 = sB[1];
        w.x = pack2bf(b0.x, b0.y); w.y = pack2bf(b0.z, b0.w);
        w.z = pack2bf(b1.x, b1.y); w.w = pack2bf(b1.z, b1.w);
        *(uint4*)((char*)Bl + off) = w;
      }
    } else {
      const unsigned char* qtile = qt + ((size_t)(blockB * 12 + kt)) * 16384;
      const unsigned char* ptile = pt + ((size_t)(blockP * 12 + kt)) * 16384;
      #pragma unroll
      for (int c2 = 0; c2 < 4; ++c2) {
        int chunk = wid * 4 + c2;
        gll16(qtile + chunk * 1024 + lane * 16, (char*)Al + chunk * 1024);
        gll16(ptile + chunk * 1024 + lane * 16, (char*)Bl + chunk * 1024);
      }
    }
    __syncthreads();
    #pragma unroll
    for (int ks = 0; ks < 2; ++ks) {
      bf16x8 bfr[4];
      #pragma unroll
      for (int n = 0; n < 4; ++n) {
        int row = dp * 64 + n * 16 + lr;
        int off = (row * 128 + ks * 64 + lg * 16) ^ ((row & 7) << 4);
        bfr[n] = *(const bf16x8*)((const char*)Bl + off);
      }
      #pragma unroll
      for (int mh = 0; mh < 2; ++mh) {   // 2-row halves: -8 VGPR vs af[4]
        bf16x8 af0, af1;
        {
          int row0 = db * 64 + (mh * 2 + 0) * 16 + lr;
          int row1 = db * 64 + (mh * 2 + 1) * 16 + lr;
          af0 = *(const bf16x8*)((const char*)Al + ((row0 * 128 + ks * 64 + lg * 16) ^ ((row0 & 7) << 4)));
          af1 = *(const bf16x8*)((const char*)Al + ((row1 * 128 + ks * 64 + lg * 16) ^ ((row1 & 7) << 4)));
        }
        #pragma unroll
        for (int n = 0; n < 4; ++n) {
          acc[mh * 2 + 0][n] = __builtin_amdgcn_mfma_f32_16x16x32_bf16(af0, bfr[n], acc[mh * 2 + 0][n], 0, 0, 0);
          acc[mh * 2 + 1][n] = __builtin_amdgcn_mfma_f32_16x16x32_bf16(af1, bfr[n], acc[mh * 2 + 1][n], 0, 0, 0);
        }
      }
    }
    __syncthreads();
  }

  // ---- wave-parallel selection (no block barriers from here on) ----
  const int outIdx = (blockB * 2 + db) * 128 + (blockP * 2 + dp);
  if (n_pair == 0) {
    if (lane == 0) out[outIdx] = -1e9f;
    return;
  }

  // per-lane validity of the 64 owned elements, as two u32 (idx=(m*4+n)*4+j)
  unsigned vlo = 0, vhi = 0;
  {
    unsigned qn[4], pc[4];
    #pragma unroll
    for (int m = 0; m < 4; ++m) qn[m] = (unsigned)((qb >> (m * 16 + lg * 4)) & 0xFull);
    #pragma unroll
    for (int n = 0; n < 4; ++n) pc[n] = ((pb >> (n * 16 + lr)) & 1ull) ? 0xFu : 0u;
    #pragma unroll
    for (int m = 0; m < 2; ++m)
      #pragma unroll
      for (int n = 0; n < 4; ++n) vlo |= (qn[m] & pc[n]) << ((m * 4 + n) * 4);
    #pragma unroll
    for (int m = 2; m < 4; ++m)
      #pragma unroll
      for (int n = 0; n < 4; ++n) vhi |= (qn[m] & pc[n]) << (((m - 2) * 4 + n) * 4);
  }
  #define VBIT(idx) ((idx) < 32 ? ((vlo >> (idx)) & 1u) : ((vhi >> ((idx) - 32)) & 1u))

  // T1: masked sum / min / max
  float tsum = 0.f, mn = INFINITY, mx = -INFINITY;
  #pragma unroll
  for (int m = 0; m < 4; ++m)
    #pragma unroll
    for (int n = 0; n < 4; ++n)
      #pragma unroll
      for (int j = 0; j < 4; ++j) {
        const int idx = (m * 4 + n) * 4 + j;
        float x = acc[m][n][j];
        if (VBIT(idx)) { tsum += x; mn = fminf(mn, x); mx = fmaxf(mx, x); }
      }
  #pragma unroll
  for (int off = 1; off < 64; off <<= 1) {
    tsum += __shfl_xor(tsum, off);
    mn = fminf(mn, __shfl_xor(mn, off));
    mx = fmaxf(mx, __shfl_xor(mx, off));
  }

  int ksel = 4 * n_pair / 10; if (ksel < 1) ksel = 1;
  int lsel = 2 * n_pair / 10; if (lsel < 1) lsel = 1;

  unsigned* hC = (unsigned*)(arena + wid * 2048);
  float* hS = (float*)(arena + wid * 2048 + 1024);
  float* listT = (float*)(arena + 8192 + wid * 512);
  float* listB = listT + 64;

  float topS, botS;
  if (!(mx > mn)) {
    topS = (float)ksel * mn;   // all valid values equal
    botS = (float)lsel * mn;
  } else {
    // T2: count+sum histogram, bins packed into registers
    ((uint4*)hC)[lane] = uint4{0u, 0u, 0u, 0u};
    ((float4*)hS)[lane] = float4{0.f, 0.f, 0.f, 0.f};
    const float sc0 = 255.0f / (mx - mn);
    unsigned bpk[16];
    #pragma unroll
    for (int m = 0; m < 4; ++m)
      #pragma unroll
      for (int n = 0; n < 4; ++n) {
        unsigned wv = 0;
        #pragma unroll
        for (int j = 0; j < 4; ++j) {
          const int idx = (m * 4 + n) * 4 + j;
          float x = acc[m][n][j];
          int b = (int)((x - mn) * sc0);
          b = b < 0 ? 0 : (b > 255 ? 255 : b);
          wv |= (unsigned)b << (8 * j);
          if (VBIT(idx)) { atomicAdd(&hC[b], 1u); atomicAdd(&hS[b], x); }
        }
        bpk[m * 4 + n] = wv;
      }

    int sbT, RT, cT; float sumA;
    int sbB, RB, cB; float sumB;
    scanTopSum(hC, hS, lane, ksel, sbT, RT, cT, sumA);
    scanBotSum(hC, hS, lane, lsel, sbB, RB, cB, sumB);

    // T3: extract candidates for both bins; build alive masks for fallback
    if (lane == 0) { lcnt[wid * 2] = 0u; lcnt[wid * 2 + 1] = 0u; }
    ull aT = 0, aB = 0;
    const bool gT = (cT <= 64), gB = (cB <= 64);
    #pragma unroll
    for (int m = 0; m < 4; ++m)
      #pragma unroll
      for (int n = 0; n < 4; ++n)
        #pragma unroll
        for (int j = 0; j < 4; ++j) {
          const int idx = (m * 4 + n) * 4 + j;
          int b = (int)((bpk[m * 4 + n] >> (8 * j)) & 255u);
          bool v = VBIT(idx) != 0u;
          bool isT = v && (b == sbT);
          bool isB = v && (b == sbB);
          aT |= ((ull)isT) << idx;
          aB |= ((ull)isB) << idx;
          if (isT && gT) { unsigned p = atomicAdd(&lcnt[wid * 2], 1u); listT[p] = acc[m][n][j]; }
          if (isB && gB) { unsigned p = atomicAdd(&lcnt[wid * 2 + 1], 1u); listB[p] = acc[m][n][j]; }
        }

    const float w0 = (mx - mn) * (1.0f / 255.0f);

    // cold exact fallback when the rank bin holds >64 members
    auto fbSum = [&](ull alive0, float lo0, int R0, int c0, bool largest,
                     float* listp, unsigned* lcp) -> float {
      ull alive = alive0; float lo = lo0, hi = lo0 + w0;
      int R = R0, c = c0;
      for (int lev = 0; lev < 3 && c > 64 && (hi > lo); ++lev) {
        ((uint4*)hC)[lane] = uint4{0u, 0u, 0u, 0u};
        float sc = 255.0f / (hi - lo);
        #pragma unroll
        for (int m = 0; m < 4; ++m)
          #pragma unroll
          for (int n = 0; n < 4; ++n)
            #pragma unroll
            for (int j = 0; j < 4; ++j) {
              const int idx = (m * 4 + n) * 4 + j;
              if ((alive >> idx) & 1ull) {
                int b = (int)((acc[m][n][j] - lo) * sc);
                b = b < 0 ? 0 : (b > 255 ? 255 : b);
                atomicAdd(&hC[b], 1u);
              }
            }
        int sb2, r2, c2;
        scanCount(hC, lane, R, largest, sb2, r2, c2);
        ull na = 0;
        #pragma unroll
        for (int m = 0; m < 4; ++m)
          #pragma unroll
          for (int n = 0; n < 4; ++n)
            #pragma unroll
            for (int j = 0; j < 4; ++j) {
              const int idx = (m * 4 + n) * 4 + j;
              if ((alive >> idx) & 1ull) {
                int b = (int)((acc[m][n][j] - lo) * sc);
                b = b < 0 ? 0 : (b > 255 ? 255 : b);
                na |= ((ull)(b == sb2)) << idx;
              }
            }
        alive = na; R = r2; c = c2;
        float w = (hi - lo) * (1.0f / 255.0f);
        float nlo = lo + w * (float)sb2;
        hi = nlo + w; lo = nlo;
      }
      float tval;
      if (c > 64) tval = lo;   // needs >64 bitwise-identical values; error <= w0/255^2
      else {
        if (lane == 0) *lcp = 0u;
        #pragma unroll
        for (int m = 0; m < 4; ++m)
          #pragma unroll
          for (int n = 0; n < 4; ++n)
            #pragma unroll
            for (int j = 0; j < 4; ++j) {
              const int idx = (m * 4 + n) * 4 + j;
              if ((alive >> idx) & 1ull) {
                unsigned p = atomicAdd(lcp, 1u);
                listp[p] = acc[m][n][j];
              }
            }
        tval = rankSelect(listp, c, R, largest, lane);
      }
      // exact sum over the ORIGINAL bin members vs tval
      float s = 0.f; int cnt = 0;
      #pragma unroll
      for (int m = 0; m < 4; ++m)
        #pragma unroll
        for (int n = 0; n < 4; ++n)
          #pragma unroll
          for (int j = 0; j < 4; ++j) {
            const int idx = (m * 4 + n) * 4 + j;
            if ((alive0 >> idx) & 1ull) {
              float x = acc[m][n][j];
              bool sel = largest ? (x > tval) : (x < tval);
              s += sel ? x : 0.f; cnt += sel;
            }
          }
      #pragma unroll
      for (int off = 1; off < 64; off <<= 1) {
        s += __shfl_xor(s, off);
        cnt += __shfl_xor(cnt, off);
      }
      return s + tval * (float)(R0 - cnt);
    };

    float inT = gT ? rankSum(listT, cT, RT, true, lane)
                   : fbSum(aT, mn + w0 * (float)sbT, RT, cT, true, listT, &lcnt[wid * 2]);
    float inB = gB ? rankSum(listB, cB, RB, false, lane)
                   : fbSum(aB, mn + w0 * (float)sbB, RB, cB, false, listB, &lcnt[wid * 2 + 1]);
    topS = sumA + inT;
    botS = sumB + inB;
  }
  #undef VBIT

  if (lane == 0) {
    float alpha = log1pf(expf(alpha_raw[0]));
    float beta = log1pf(expf(beta_raw[0]));
    float total_mean = tsum / (float)n_pair;
    float top_mean = topS / (float)ksel;
    float bm = fmaxf(0.0f, -(botS / (float)lsel));
    out[outIdx] = total_mean + alpha * top_mean - beta * bm;
  }
}

extern "C" void kernel_launch(void* const* d_in, const int* in_sizes, int n_in,
                              void* d_out, int out_size, void* d_ws, size_t ws_size,
                              hipStream_t stream) {
  (void)in_sizes; (void)n_in; (void)out_size;
  const float* q_emb = (const float*)d_in[0];
  const float* p_emb = (const float*)d_in[1];
  const void* q_mask = d_in[2];
  const void* p_mask = d_in[3];
  const float* alpha_raw = (const float*)d_in[4];
  const float* beta_raw = (const float*)d_in[5];
  float* out = (float*)d_out;

  const size_t needWs = ((size_t)(NA_G + NB_G)) * 16;  // 18.87 MB bf16 tiles
  if (ws_size >= needWs) {
    unsigned char* qt = (unsigned char*)d_ws;
    unsigned char* pt = qt + (size_t)NA_G * 16;
    hipLaunchKernelGGL(convert_pack, dim3((NA_G + NB_G) / 256), dim3(256), 0, stream,
                       q_emb, p_emb, qt, pt);
    hipLaunchKernelGGL((dpr_fused<1>), dim3(2048), dim3(TB), 0, stream,
                       q_emb, p_emb, q_mask, p_mask, alpha_raw, beta_raw, qt, pt, out);
  } else {
    hipLaunchKernelGGL((dpr_fused<0>), dim3(2048), dim3(TB), 0, stream,
                       q_emb, p_emb, q_mask, p_mask, alpha_raw, beta_raw,
                       (const unsigned char*)nullptr, (const unsigned char*)nullptr, out);
  }
}

// Round 5
// 236.896 us; speedup vs baseline: 1.1870x; 1.1839x over previous
//
#include <hip/hip_runtime.h>

#define TB 256
#define NA_G (32 * 12 * 1024)   // 16B-groups in A tiles
#define NB_G (64 * 12 * 1024)   // 16B-groups in B tiles

typedef __bf16 bf16x8 __attribute__((ext_vector_type(8)));
typedef float f32x4 __attribute__((ext_vector_type(4)));
typedef unsigned long long ull;

__device__ __forceinline__ unsigned pack2bf(float a, float b) {
  unsigned ua = __float_as_uint(a), ub = __float_as_uint(b);
  ua = (ua + 0x7fffu + ((ua >> 16) & 1u)) >> 16;   // RNE f32->bf16
  ub = (ub + 0x7fffu + ((ub >> 16) & 1u)) >> 16;
  return ua | (ub << 16);
}

__device__ __forceinline__ void gll16(const void* g, void* l) {
  __builtin_amdgcn_global_load_lds(
      (const __attribute__((address_space(1))) unsigned*)g,
      (__attribute__((address_space(3))) unsigned*)l, 16, 0, 0);
}

// Pre-convert f32 -> bf16 into swizzled 128x64 tiles (LDS-image layout).
__global__ __launch_bounds__(256) void convert_pack(
    const float* __restrict__ q, const float* __restrict__ p,
    unsigned char* __restrict__ qt, unsigned char* __restrict__ pt) {
  int g = blockIdx.x * 256 + threadIdx.x;
  const float* src;
  unsigned char* dst;
  if (g < NA_G) { src = q; dst = qt; }
  else { g -= NA_G; src = p; dst = pt; }
  int tile = g >> 10;
  int o = (g & 1023) * 16;                 // byte offset in 16KB tile
  int row = o >> 7;
  int colb = (o & 127) ^ ((row & 7) << 4); // inverse of XOR swizzle
  int rb = tile / 12, kt = tile - rb * 12;
  const float* s = src + ((size_t)(rb * 128 + row)) * 768 + kt * 64 + (colb >> 1);
  float4 a = ((const float4*)s)[0];
  float4 b = ((const float4*)s)[1];
  uint4 w;
  w.x = pack2bf(a.x, a.y); w.y = pack2bf(a.z, a.w);
  w.z = pack2bf(b.x, b.y); w.w = pack2bf(b.z, b.w);
  *(uint4*)(dst + (size_t)tile * 16384 + o) = w;
}

// suffix-scan (from top): find bin holding rank R; return bin id, rank-in-bin,
// bin count, exact sum of bins strictly above, and the bin's own value-sum.
__device__ __forceinline__ void scanTopSum(const unsigned* hC, const float* hS,
                                           int lane, int R, int& selB, int& Rin,
                                           int& cnt, float& sumAbove, float& binSum) {
  uint4 c4 = ((const uint4*)hC)[lane];
  float4 s4 = ((const float4*)hS)[lane];
  unsigned lc = c4.x + c4.y + c4.z + c4.w;
  float ls = s4.x + s4.y + s4.z + s4.w;
  unsigned run = lc; float runv = ls;
  #pragma unroll
  for (int off = 1; off < 64; off <<= 1) {
    unsigned o = __shfl_down(run, off);
    float ov = __shfl_down(runv, off);
    if (lane + off < 64) { run += o; runv += ov; }
  }
  unsigned above = run - lc; float vabove = runv - ls;
  bool found = ((unsigned)R > above) && ((unsigned)R <= run);
  int sb = 0, ri = 0, cc = 0; float sa = 0.f, bs = 0.f;
  if (found) {
    unsigned a = above; float va = vabove;
    if ((unsigned)R <= a + c4.w) { sb = 3; ri = R - (int)a; cc = (int)c4.w; sa = va; bs = s4.w; }
    else { a += c4.w; va += s4.w;
    if ((unsigned)R <= a + c4.z) { sb = 2; ri = R - (int)a; cc = (int)c4.z; sa = va; bs = s4.z; }
    else { a += c4.z; va += s4.z;
    if ((unsigned)R <= a + c4.y) { sb = 1; ri = R - (int)a; cc = (int)c4.y; sa = va; bs = s4.y; }
    else { a += c4.y; va += s4.y; sb = 0; ri = R - (int)a; cc = (int)c4.x; sa = va; bs = s4.x; } } }
    sb += lane * 4;
  }
  ull fm = __ballot(found);
  int src = fm ? (int)__builtin_ctzll(fm) : 0;
  selB = __shfl(sb, src); Rin = __shfl(ri, src);
  cnt = __shfl(cc, src); sumAbove = __shfl(sa, src); binSum = __shfl(bs, src);
}

__device__ __forceinline__ void scanBotSum(const unsigned* hC, const float* hS,
                                           int lane, int R, int& selB, int& Rin,
                                           int& cnt, float& sumBelow, float& binSum) {
  uint4 c4 = ((const uint4*)hC)[lane];
  float4 s4 = ((const float4*)hS)[lane];
  unsigned lc = c4.x + c4.y + c4.z + c4.w;
  float ls = s4.x + s4.y + s4.z + s4.w;
  unsigned run = lc; float runv = ls;
  #pragma unroll
  for (int off = 1; off < 64; off <<= 1) {
    unsigned o = __shfl_up(run, off);
    float ov = __shfl_up(runv, off);
    if (lane >= off) { run += o; runv += ov; }
  }
  unsigned below = run - lc; float vbelow = runv - ls;
  bool found = ((unsigned)R > below) && ((unsigned)R <= run);
  int sb = 0, ri = 0, cc = 0; float sa = 0.f, bs = 0.f;
  if (found) {
    unsigned a = below; float va = vbelow;
    if ((unsigned)R <= a + c4.x) { sb = 0; ri = R - (int)a; cc = (int)c4.x; sa = va; bs = s4.x; }
    else { a += c4.x; va += s4.x;
    if ((unsigned)R <= a + c4.y) { sb = 1; ri = R - (int)a; cc = (int)c4.y; sa = va; bs = s4.y; }
    else { a += c4.y; va += s4.y;
    if ((unsigned)R <= a + c4.z) { sb = 2; ri = R - (int)a; cc = (int)c4.z; sa = va; bs = s4.z; }
    else { a += c4.z; va += s4.z; sb = 3; ri = R - (int)a; cc = (int)c4.w; sa = va; bs = s4.w; } } }
    sb += lane * 4;
  }
  ull fm = __ballot(found);
  int src = fm ? (int)__builtin_ctzll(fm) : 0;
  selB = __shfl(sb, src); Rin = __shfl(ri, src);
  cnt = __shfl(cc, src); sumBelow = __shfl(sa, src); binSum = __shfl(bs, src);
}

template <int PATH>
__global__ __launch_bounds__(TB, 3) void dpr_fused(
    const float* __restrict__ q_emb, const float* __restrict__ p_emb,
    const void* __restrict__ qmr, const void* __restrict__ pmr,
    const float* __restrict__ alpha_raw, const float* __restrict__ beta_raw,
    const unsigned char* __restrict__ qt, const unsigned char* __restrict__ pt,
    float* __restrict__ out) {
  const int H = 768;
  // GEMM phase: Al|Bl (32 KB). Selection phase (after final barrier): 4 wave-
  // private 2KB {count[256]|sum[256]} histograms alias the front of the arena.
  __shared__ __align__(16) char arena[32768];
  unsigned short* Al = (unsigned short*)arena;
  unsigned short* Bl = (unsigned short*)(arena + 16384);

  const int tid = threadIdx.x, lane = tid & 63, wid = tid >> 6;
  const int bid = blockIdx.x, blockB = bid >> 6, blockP = bid & 63;
  const int lr = lane & 15, lg = lane >> 4;
  const int db = wid >> 1, dp = wid & 1;

  // ---- per-wave masks (dtype sniffed) ----
  bool m32 = true;
  {
    const unsigned* qm32 = (const unsigned*)qmr;
    #pragma unroll
    for (int i = 0; i < 8; ++i) m32 = m32 && (qm32[i] <= 1u);
  }
  int qrow = (blockB * 2 + db) * 64 + lane;
  int pcolg = (blockP * 2 + dp) * 64 + lane;
  bool qvb = m32 ? (((const int*)qmr)[qrow] != 0) : (((const unsigned char*)qmr)[qrow] != 0);
  bool pvb = m32 ? (((const int*)pmr)[pcolg] != 0) : (((const unsigned char*)pmr)[pcolg] != 0);
  ull qb = __ballot(qvb);
  ull pb = __ballot(pvb);
  const int n_pair = __popcll(qb) * __popcll(pb);

  // ---- GEMM: 128x128 block tile, each wave owns one 64x64 pair ----
  f32x4 acc[4][4];
  #pragma unroll
  for (int m = 0; m < 4; ++m)
    #pragma unroll
    for (int n = 0; n < 4; ++n)
      acc[m][n] = f32x4{0.f, 0.f, 0.f, 0.f};

  const float* Abase = q_emb + (size_t)(blockB * 128) * H;
  const float* Bbase = p_emb + (size_t)(blockP * 128) * H;

  for (int kt = 0; kt < 12; ++kt) {
    if (PATH == 0) {
      const int k0 = kt * 64;
      #pragma unroll
      for (int it = 0; it < 4; ++it) {
        int g = tid + 256 * it;
        int row = g >> 3;
        int col = (g & 7) * 8;
        int off = (row * 128 + col * 2) ^ ((row & 7) << 4);
        const float4* sA = (const float4*)(Abase + (size_t)row * H + k0 + col);
        float4 a0 = sA[0], a1 = sA[1];
        uint4 w;
        w.x = pack2bf(a0.x, a0.y); w.y = pack2bf(a0.z, a0.w);
        w.z = pack2bf(a1.x, a1.y); w.w = pack2bf(a1.z, a1.w);
        *(uint4*)((char*)Al + off) = w;
        const float4* sB = (const float4*)(Bbase + (size_t)row * H + k0 + col);
        float4 b0 = sB[0], b1 = sB[1];
        w.x = pack2bf(b0.x, b0.y); w.y = pack2bf(b0.z, b0.w);
        w.z = pack2bf(b1.x, b1.y); w.w = pack2bf(b1.z, b1.w);
        *(uint4*)((char*)Bl + off) = w;
      }
    } else {
      const unsigned char* qtile = qt + ((size_t)(blockB * 12 + kt)) * 16384;
      const unsigned char* ptile = pt + ((size_t)(blockP * 12 + kt)) * 16384;
      #pragma unroll
      for (int c2 = 0; c2 < 4; ++c2) {
        int chunk = wid * 4 + c2;
        gll16(qtile + chunk * 1024 + lane * 16, (char*)Al + chunk * 1024);
        gll16(ptile + chunk * 1024 + lane * 16, (char*)Bl + chunk * 1024);
      }
    }
    __syncthreads();
    #pragma unroll
    for (int ks = 0; ks < 2; ++ks) {
      bf16x8 bfr[4];
      #pragma unroll
      for (int n = 0; n < 4; ++n) {
        int row = dp * 64 + n * 16 + lr;
        int off = (row * 128 + ks * 64 + lg * 16) ^ ((row & 7) << 4);
        bfr[n] = *(const bf16x8*)((const char*)Bl + off);
      }
      #pragma unroll
      for (int mh = 0; mh < 2; ++mh) {
        bf16x8 af0, af1;
        {
          int row0 = db * 64 + (mh * 2 + 0) * 16 + lr;
          int row1 = db * 64 + (mh * 2 + 1) * 16 + lr;
          af0 = *(const bf16x8*)((const char*)Al + ((row0 * 128 + ks * 64 + lg * 16) ^ ((row0 & 7) << 4)));
          af1 = *(const bf16x8*)((const char*)Al + ((row1 * 128 + ks * 64 + lg * 16) ^ ((row1 & 7) << 4)));
        }
        #pragma unroll
        for (int n = 0; n < 4; ++n) {
          acc[mh * 2 + 0][n] = __builtin_amdgcn_mfma_f32_16x16x32_bf16(af0, bfr[n], acc[mh * 2 + 0][n], 0, 0, 0);
          acc[mh * 2 + 1][n] = __builtin_amdgcn_mfma_f32_16x16x32_bf16(af1, bfr[n], acc[mh * 2 + 1][n], 0, 0, 0);
        }
      }
    }
    __syncthreads();   // final one also fences arena reuse below
  }

  // ---- wave-parallel selection: pure histogram, no gather/rank loops ----
  const int outIdx = (blockB * 2 + db) * 128 + (blockP * 2 + dp);
  if (n_pair == 0) {
    if (lane == 0) out[outIdx] = -1e9f;
    return;
  }

  // per-lane validity of the 64 owned elements, as two u32 (idx=(m*4+n)*4+j)
  unsigned vlo = 0, vhi = 0;
  {
    unsigned qn[4], pc[4];
    #pragma unroll
    for (int m = 0; m < 4; ++m) qn[m] = (unsigned)((qb >> (m * 16 + lg * 4)) & 0xFull);
    #pragma unroll
    for (int n = 0; n < 4; ++n) pc[n] = ((pb >> (n * 16 + lr)) & 1ull) ? 0xFu : 0u;
    #pragma unroll
    for (int m = 0; m < 2; ++m)
      #pragma unroll
      for (int n = 0; n < 4; ++n) vlo |= (qn[m] & pc[n]) << ((m * 4 + n) * 4);
    #pragma unroll
    for (int m = 2; m < 4; ++m)
      #pragma unroll
      for (int n = 0; n < 4; ++n) vhi |= (qn[m] & pc[n]) << (((m - 2) * 4 + n) * 4);
  }
  #define VBIT(idx) ((idx) < 32 ? ((vlo >> (idx)) & 1u) : ((vhi >> ((idx) - 32)) & 1u))

  // masked sum / min / max
  float tsum = 0.f, mn = INFINITY, mx = -INFINITY;
  #pragma unroll
  for (int m = 0; m < 4; ++m)
    #pragma unroll
    for (int n = 0; n < 4; ++n)
      #pragma unroll
      for (int j = 0; j < 4; ++j) {
        const int idx = (m * 4 + n) * 4 + j;
        float x = acc[m][n][j];
        if (VBIT(idx)) { tsum += x; mn = fminf(mn, x); mx = fmaxf(mx, x); }
      }
  #pragma unroll
  for (int off = 1; off < 64; off <<= 1) {
    tsum += __shfl_xor(tsum, off);
    mn = fminf(mn, __shfl_xor(mn, off));
    mx = fmaxf(mx, __shfl_xor(mx, off));
  }

  int ksel = 4 * n_pair / 10; if (ksel < 1) ksel = 1;
  int lsel = 2 * n_pair / 10; if (lsel < 1) lsel = 1;

  unsigned* hC = (unsigned*)(arena + wid * 2048);
  float* hS = (float*)(arena + wid * 2048 + 1024);

  float topS, botS;
  if (!(mx > mn)) {
    topS = (float)ksel * mn;   // all valid values identical
    botS = (float)lsel * mn;
  } else {
    const float w0 = (mx - mn) * (1.0f / 256.0f);
    const float sc0 = 1.0f / w0;

    // level-0: count + value-sum histogram over all valid values
    ((uint4*)hC)[lane] = uint4{0u, 0u, 0u, 0u};
    ((float4*)hS)[lane] = float4{0.f, 0.f, 0.f, 0.f};
    #pragma unroll
    for (int m = 0; m < 4; ++m)
      #pragma unroll
      for (int n = 0; n < 4; ++n)
        #pragma unroll
        for (int j = 0; j < 4; ++j) {
          const int idx = (m * 4 + n) * 4 + j;
          if (VBIT(idx)) {
            float x = acc[m][n][j];
            int b = (int)((x - mn) * sc0);
            b = b < 0 ? 0 : (b > 255 ? 255 : b);
            atomicAdd(&hC[b], 1u);
            atomicAdd(&hS[b], x);
          }
        }

    int sbT, RT, cT; float sumA, sBinT;
    int sbB, RB, cB; float sumBlw, sBinB;
    scanTopSum(hC, hS, lane, ksel, sbT, RT, cT, sumA, sBinT);
    scanBotSum(hC, hS, lane, lsel, sbB, RB, cB, sumBlw, sBinB);

    // level-1 refinement: sub-histogram the rank bin; take sub-bin-mean tail.
    // Residual error <= c2 * range/65536 on the SUM (~1e-3), /ksel afterwards.
    auto refine = [&](bool largest, int sb0, int R0, int c0, float binSum0) -> float {
      if (R0 >= c0) return binSum0;                      // whole bin selected: exact
      float lo1 = mn + w0 * (float)sb0;
      if (!(w0 > 0.f)) return binSum0 * ((float)R0 / (float)c0);
      ((uint4*)hC)[lane] = uint4{0u, 0u, 0u, 0u};
      ((float4*)hS)[lane] = float4{0.f, 0.f, 0.f, 0.f};
      const float sc1 = 256.0f / w0;
      #pragma unroll
      for (int m = 0; m < 4; ++m)
        #pragma unroll
        for (int n = 0; n < 4; ++n)
          #pragma unroll
          for (int j = 0; j < 4; ++j) {
            const int idx = (m * 4 + n) * 4 + j;
            if (VBIT(idx)) {
              float x = acc[m][n][j];
              int b0e = (int)((x - mn) * sc0);
              b0e = b0e < 0 ? 0 : (b0e > 255 ? 255 : b0e);
              if (b0e == sb0) {
                int b1 = (int)((x - lo1) * sc1);
                b1 = b1 < 0 ? 0 : (b1 > 255 ? 255 : b1);
                atomicAdd(&hC[b1], 1u);
                atomicAdd(&hS[b1], x);
              }
            }
          }
      int sb2, R2, c2; float above2, bs2;
      if (largest) scanTopSum(hC, hS, lane, R0, sb2, R2, c2, above2, bs2);
      else         scanBotSum(hC, hS, lane, R0, sb2, R2, c2, above2, bs2);
      if (c2 <= 0) return binSum0 * ((float)R0 / (float)c0);  // paranoia
      return above2 + bs2 * ((float)R2 / (float)c2);
    };

    topS = sumA + refine(true, sbT, RT, cT, sBinT);
    botS = sumBlw + refine(false, sbB, RB, cB, sBinB);
  }
  #undef VBIT

  if (lane == 0) {
    float alpha = log1pf(expf(alpha_raw[0]));
    float beta = log1pf(expf(beta_raw[0]));
    float total_mean = tsum / (float)n_pair;
    float top_mean = topS / (float)ksel;
    float bm = fmaxf(0.0f, -(botS / (float)lsel));
    out[outIdx] = total_mean + alpha * top_mean - beta * bm;
  }
}

extern "C" void kernel_launch(void* const* d_in, const int* in_sizes, int n_in,
                              void* d_out, int out_size, void* d_ws, size_t ws_size,
                              hipStream_t stream) {
  (void)in_sizes; (void)n_in; (void)out_size;
  const float* q_emb = (const float*)d_in[0];
  const float* p_emb = (const float*)d_in[1];
  const void* q_mask = d_in[2];
  const void* p_mask = d_in[3];
  const float* alpha_raw = (const float*)d_in[4];
  const float* beta_raw = (const float*)d_in[5];
  float* out = (float*)d_out;

  const size_t needWs = ((size_t)(NA_G + NB_G)) * 16;  // 18.87 MB bf16 tiles
  if (ws_size >= needWs) {
    unsigned char* qt = (unsigned char*)d_ws;
    unsigned char* pt = qt + (size_t)NA_G * 16;
    hipLaunchKernelGGL(convert_pack, dim3((NA_G + NB_G) / 256), dim3(256), 0, stream,
                       q_emb, p_emb, qt, pt);
    hipLaunchKernelGGL((dpr_fused<1>), dim3(2048), dim3(TB), 0, stream,
                       q_emb, p_emb, q_mask, p_mask, alpha_raw, beta_raw, qt, pt, out);
  } else {
    hipLaunchKernelGGL((dpr_fused<0>), dim3(2048), dim3(TB), 0, stream,
                       q_emb, p_emb, q_mask, p_mask, alpha_raw, beta_raw,
                       (const unsigned char*)nullptr, (const unsigned char*)nullptr, out);
  }
}

// Round 6
// 230.086 us; speedup vs baseline: 1.2221x; 1.0296x over previous
//
#include <hip/hip_runtime.h>

#define TB 256
#define NA_G (32 * 12 * 1024)   // 16B-groups in A tiles
#define NB_G (64 * 12 * 1024)   // 16B-groups in B tiles

typedef __bf16 bf16x8 __attribute__((ext_vector_type(8)));
typedef float f32x4 __attribute__((ext_vector_type(4)));
typedef unsigned long long ull;

__device__ __forceinline__ unsigned pack2bf(float a, float b) {
  unsigned ua = __float_as_uint(a), ub = __float_as_uint(b);
  ua = (ua + 0x7fffu + ((ua >> 16) & 1u)) >> 16;   // RNE f32->bf16
  ub = (ub + 0x7fffu + ((ub >> 16) & 1u)) >> 16;
  return ua | (ub << 16);
}

// Pre-convert f32 -> bf16 into FRAGMENT-CONTIGUOUS 16KB tiles:
// tile t = (rb, kt): frag f = (rb2*2 + ks), f*1024 + lane*16 holds
// src row rb*128 + rb2*16 + (lane&15), cols kt*64 + ks*32 + (lane>>4)*8 .. +8
__global__ __launch_bounds__(256) void convert_pack(
    const float* __restrict__ q, const float* __restrict__ p,
    unsigned char* __restrict__ qt, unsigned char* __restrict__ pt) {
  int g = blockIdx.x * 256 + threadIdx.x;
  const float* src;
  unsigned char* dst;
  if (g < NA_G) { src = q; dst = qt; }
  else { g -= NA_G; src = p; dst = pt; }
  int tile = g >> 10;
  int o = g & 1023;                 // 16B-group within tile
  int f = o >> 6, l = o & 63;
  int rb2 = f >> 1, ks = f & 1;
  int lr = l & 15, lg = l >> 4;
  int rb = tile / 12, kt = tile - rb * 12;
  const float* s = src + (size_t)(rb * 128 + rb2 * 16 + lr) * 768 + kt * 64 + ks * 32 + lg * 8;
  float4 a = ((const float4*)s)[0];
  float4 b = ((const float4*)s)[1];
  uint4 w;
  w.x = pack2bf(a.x, a.y); w.y = pack2bf(a.z, a.w);
  w.z = pack2bf(b.x, b.y); w.w = pack2bf(b.z, b.w);
  *(uint4*)(dst + (size_t)tile * 16384 + (size_t)o * 16) = w;
}

// suffix-scan (from top): find bin holding rank R; return bin id, rank-in-bin,
// bin count, exact sum of bins strictly above, and the bin's own value-sum.
__device__ __forceinline__ void scanTopSum(const unsigned* hC, const float* hS,
                                           int lane, int R, int& selB, int& Rin,
                                           int& cnt, float& sumAbove, float& binSum) {
  uint4 c4 = ((const uint4*)hC)[lane];
  float4 s4 = ((const float4*)hS)[lane];
  unsigned lc = c4.x + c4.y + c4.z + c4.w;
  float ls = s4.x + s4.y + s4.z + s4.w;
  unsigned run = lc; float runv = ls;
  #pragma unroll
  for (int off = 1; off < 64; off <<= 1) {
    unsigned o = __shfl_down(run, off);
    float ov = __shfl_down(runv, off);
    if (lane + off < 64) { run += o; runv += ov; }
  }
  unsigned above = run - lc; float vabove = runv - ls;
  bool found = ((unsigned)R > above) && ((unsigned)R <= run);
  int sb = 0, ri = 0, cc = 0; float sa = 0.f, bs = 0.f;
  if (found) {
    unsigned a = above; float va = vabove;
    if ((unsigned)R <= a + c4.w) { sb = 3; ri = R - (int)a; cc = (int)c4.w; sa = va; bs = s4.w; }
    else { a += c4.w; va += s4.w;
    if ((unsigned)R <= a + c4.z) { sb = 2; ri = R - (int)a; cc = (int)c4.z; sa = va; bs = s4.z; }
    else { a += c4.z; va += s4.z;
    if ((unsigned)R <= a + c4.y) { sb = 1; ri = R - (int)a; cc = (int)c4.y; sa = va; bs = s4.y; }
    else { a += c4.y; va += s4.y; sb = 0; ri = R - (int)a; cc = (int)c4.x; sa = va; bs = s4.x; } } }
    sb += lane * 4;
  }
  ull fm = __ballot(found);
  int src = fm ? (int)__builtin_ctzll(fm) : 0;
  selB = __shfl(sb, src); Rin = __shfl(ri, src);
  cnt = __shfl(cc, src); sumAbove = __shfl(sa, src); binSum = __shfl(bs, src);
}

__device__ __forceinline__ void scanBotSum(const unsigned* hC, const float* hS,
                                           int lane, int R, int& selB, int& Rin,
                                           int& cnt, float& sumBelow, float& binSum) {
  uint4 c4 = ((const uint4*)hC)[lane];
  float4 s4 = ((const float4*)hS)[lane];
  unsigned lc = c4.x + c4.y + c4.z + c4.w;
  float ls = s4.x + s4.y + s4.z + s4.w;
  unsigned run = lc; float runv = ls;
  #pragma unroll
  for (int off = 1; off < 64; off <<= 1) {
    unsigned o = __shfl_up(run, off);
    float ov = __shfl_up(runv, off);
    if (lane >= off) { run += o; runv += ov; }
  }
  unsigned below = run - lc; float vbelow = runv - ls;
  bool found = ((unsigned)R > below) && ((unsigned)R <= run);
  int sb = 0, ri = 0, cc = 0; float sa = 0.f, bs = 0.f;
  if (found) {
    unsigned a = below; float va = vbelow;
    if ((unsigned)R <= a + c4.x) { sb = 0; ri = R - (int)a; cc = (int)c4.x; sa = va; bs = s4.x; }
    else { a += c4.x; va += s4.x;
    if ((unsigned)R <= a + c4.y) { sb = 1; ri = R - (int)a; cc = (int)c4.y; sa = va; bs = s4.y; }
    else { a += c4.y; va += s4.y;
    if ((unsigned)R <= a + c4.z) { sb = 2; ri = R - (int)a; cc = (int)c4.z; sa = va; bs = s4.z; }
    else { a += c4.z; va += s4.z; sb = 3; ri = R - (int)a; cc = (int)c4.w; sa = va; bs = s4.w; } } }
    sb += lane * 4;
  }
  ull fm = __ballot(found);
  int src = fm ? (int)__builtin_ctzll(fm) : 0;
  selB = __shfl(sb, src); Rin = __shfl(ri, src);
  cnt = __shfl(cc, src); sumBelow = __shfl(sa, src); binSum = __shfl(bs, src);
}

template <int PATH>
__global__ __launch_bounds__(TB, 4) void dpr_fused(
    const float* __restrict__ q_emb, const float* __restrict__ p_emb,
    const void* __restrict__ qmr, const void* __restrict__ pmr,
    const float* __restrict__ alpha_raw, const float* __restrict__ beta_raw,
    const unsigned char* __restrict__ qt, const unsigned char* __restrict__ pt,
    float* __restrict__ out) {
  // No barriers anywhere: each wave is fully independent. LDS = 4 wave-private
  // 2KB {count[256] | sum[256]} histograms only.
  __shared__ unsigned harena[4 * 512];

  const int tid = threadIdx.x, lane = tid & 63, wid = tid >> 6;
  const int bid = blockIdx.x, blockB = bid >> 6, blockP = bid & 63;
  const int lr = lane & 15, lg = lane >> 4;
  const int db = wid >> 1, dp = wid & 1;

  // ---- per-wave masks (dtype sniffed) ----
  bool m32 = true;
  {
    const unsigned* qm32 = (const unsigned*)qmr;
    #pragma unroll
    for (int i = 0; i < 8; ++i) m32 = m32 && (qm32[i] <= 1u);
  }
  int qrow = (blockB * 2 + db) * 64 + lane;
  int pcolg = (blockP * 2 + dp) * 64 + lane;
  bool qvb = m32 ? (((const int*)qmr)[qrow] != 0) : (((const unsigned char*)qmr)[qrow] != 0);
  bool pvb = m32 ? (((const int*)pmr)[pcolg] != 0) : (((const unsigned char*)pmr)[pcolg] != 0);
  ull qb = __ballot(qvb);
  ull pb = __ballot(pvb);
  const int n_pair = __popcll(qb) * __popcll(pb);

  const int outIdx = (blockB * 2 + db) * 128 + (blockP * 2 + dp);
  if (n_pair == 0) {            // no barriers -> safe to bail before GEMM
    if (lane == 0) out[outIdx] = -1e9f;
    return;
  }

  // ---- GEMM: direct global fragment loads, no LDS, no barriers ----
  f32x4 acc[4][4];
  #pragma unroll
  for (int m = 0; m < 4; ++m)
    #pragma unroll
    for (int n = 0; n < 4; ++n)
      acc[m][n] = f32x4{0.f, 0.f, 0.f, 0.f};

  if (PATH == 1) {
    // frag addr: tile(blockB*12+kt)*16KB + (db*4+m)*2048 + ks*1024 + lane*16
    const char* qbase = (const char*)qt + (((size_t)(blockB * 12)) << 14) + (db << 13) + lane * 16;
    const char* pbase = (const char*)pt + (((size_t)(blockP * 12)) << 14) + (dp << 13) + lane * 16;
    for (int kt = 0; kt < 12; ++kt) {
      #pragma unroll
      for (int ks = 0; ks < 2; ++ks) {
        const char* qa = qbase + (kt << 14) + (ks << 10);
        const char* pa = pbase + (kt << 14) + (ks << 10);
        bf16x8 af[4], bfr[4];
        #pragma unroll
        for (int m = 0; m < 4; ++m) af[m] = *(const bf16x8*)(qa + m * 2048);
        #pragma unroll
        for (int n = 0; n < 4; ++n) bfr[n] = *(const bf16x8*)(pa + n * 2048);
        #pragma unroll
        for (int m = 0; m < 4; ++m)
          #pragma unroll
          for (int n = 0; n < 4; ++n)
            acc[m][n] = __builtin_amdgcn_mfma_f32_16x16x32_bf16(af[m], bfr[n], acc[m][n], 0, 0, 0);
      }
    }
  } else {
    // fallback: direct f32 loads + on-the-fly pack (used only if ws too small)
    const float* qbase = q_emb + (size_t)(blockB * 128 + db * 64 + lr) * 768 + lg * 8;
    const float* pbase = p_emb + (size_t)(blockP * 128 + dp * 64 + lr) * 768 + lg * 8;
    for (int kt = 0; kt < 12; ++kt) {
      #pragma unroll
      for (int ks = 0; ks < 2; ++ks) {
        const int col = kt * 64 + ks * 32;
        bf16x8 af[4], bfr[4];
        #pragma unroll
        for (int m = 0; m < 4; ++m) {
          const float* s = qbase + (size_t)(m * 16) * 768 + col;
          float4 a = ((const float4*)s)[0], b = ((const float4*)s)[1];
          uint4 w;
          w.x = pack2bf(a.x, a.y); w.y = pack2bf(a.z, a.w);
          w.z = pack2bf(b.x, b.y); w.w = pack2bf(b.z, b.w);
          af[m] = __builtin_bit_cast(bf16x8, w);
        }
        #pragma unroll
        for (int n = 0; n < 4; ++n) {
          const float* s = pbase + (size_t)(n * 16) * 768 + col;
          float4 a = ((const float4*)s)[0], b = ((const float4*)s)[1];
          uint4 w;
          w.x = pack2bf(a.x, a.y); w.y = pack2bf(a.z, a.w);
          w.z = pack2bf(b.x, b.y); w.w = pack2bf(b.z, b.w);
          bfr[n] = __builtin_bit_cast(bf16x8, w);
        }
        #pragma unroll
        for (int m = 0; m < 4; ++m)
          #pragma unroll
          for (int n = 0; n < 4; ++n)
            acc[m][n] = __builtin_amdgcn_mfma_f32_16x16x32_bf16(af[m], bfr[n], acc[m][n], 0, 0, 0);
      }
    }
  }

  // ---- wave-parallel selection: two-level count+sum histogram ----
  // per-lane validity of the 64 owned elements (idx=(m*4+n)*4+j)
  unsigned vlo = 0, vhi = 0;
  {
    unsigned qn[4], pc[4];
    #pragma unroll
    for (int m = 0; m < 4; ++m) qn[m] = (unsigned)((qb >> (m * 16 + lg * 4)) & 0xFull);
    #pragma unroll
    for (int n = 0; n < 4; ++n) pc[n] = ((pb >> (n * 16 + lr)) & 1ull) ? 0xFu : 0u;
    #pragma unroll
    for (int m = 0; m < 2; ++m)
      #pragma unroll
      for (int n = 0; n < 4; ++n) vlo |= (qn[m] & pc[n]) << ((m * 4 + n) * 4);
    #pragma unroll
    for (int m = 2; m < 4; ++m)
      #pragma unroll
      for (int n = 0; n < 4; ++n) vhi |= (qn[m] & pc[n]) << (((m - 2) * 4 + n) * 4);
  }
  #define VBIT(idx) ((idx) < 32 ? ((vlo >> (idx)) & 1u) : ((vhi >> ((idx) - 32)) & 1u))

  // masked sum / min / max
  float tsum = 0.f, mn = INFINITY, mx = -INFINITY;
  #pragma unroll
  for (int m = 0; m < 4; ++m)
    #pragma unroll
    for (int n = 0; n < 4; ++n)
      #pragma unroll
      for (int j = 0; j < 4; ++j) {
        const int idx = (m * 4 + n) * 4 + j;
        float x = acc[m][n][j];
        if (VBIT(idx)) { tsum += x; mn = fminf(mn, x); mx = fmaxf(mx, x); }
      }
  #pragma unroll
  for (int off = 1; off < 64; off <<= 1) {
    tsum += __shfl_xor(tsum, off);
    mn = fminf(mn, __shfl_xor(mn, off));
    mx = fmaxf(mx, __shfl_xor(mx, off));
  }

  int ksel = 4 * n_pair / 10; if (ksel < 1) ksel = 1;
  int lsel = 2 * n_pair / 10; if (lsel < 1) lsel = 1;

  unsigned* hC = &harena[wid * 512];
  float* hS = (float*)&harena[wid * 512 + 256];

  float topS, botS;
  if (!(mx > mn)) {
    topS = (float)ksel * mn;   // all valid values identical
    botS = (float)lsel * mn;
  } else {
    const float w0 = (mx - mn) * (1.0f / 256.0f);
    const float sc0 = 1.0f / w0;

    // level-0: count + value-sum histogram over all valid values
    ((uint4*)hC)[lane] = uint4{0u, 0u, 0u, 0u};
    ((float4*)hS)[lane] = float4{0.f, 0.f, 0.f, 0.f};
    #pragma unroll
    for (int m = 0; m < 4; ++m)
      #pragma unroll
      for (int n = 0; n < 4; ++n)
        #pragma unroll
        for (int j = 0; j < 4; ++j) {
          const int idx = (m * 4 + n) * 4 + j;
          if (VBIT(idx)) {
            float x = acc[m][n][j];
            int b = (int)((x - mn) * sc0);
            b = b < 0 ? 0 : (b > 255 ? 255 : b);
            atomicAdd(&hC[b], 1u);
            atomicAdd(&hS[b], x);
          }
        }

    int sbT, RT, cT; float sumA, sBinT;
    int sbB, RB, cB; float sumBlw, sBinB;
    scanTopSum(hC, hS, lane, ksel, sbT, RT, cT, sumA, sBinT);
    scanBotSum(hC, hS, lane, lsel, sbB, RB, cB, sumBlw, sBinB);

    // level-1 refinement: sub-histogram the rank bin; sub-bin-mean tail.
    auto refine = [&](bool largest, int sb0, int R0, int c0, float binSum0) -> float {
      if (R0 >= c0) return binSum0;                      // whole bin: exact
      float lo1 = mn + w0 * (float)sb0;
      if (!(w0 > 0.f)) return binSum0 * ((float)R0 / (float)c0);
      ((uint4*)hC)[lane] = uint4{0u, 0u, 0u, 0u};
      ((float4*)hS)[lane] = float4{0.f, 0.f, 0.f, 0.f};
      const float sc1 = 256.0f / w0;
      #pragma unroll
      for (int m = 0; m < 4; ++m)
        #pragma unroll
        for (int n = 0; n < 4; ++n)
          #pragma unroll
          for (int j = 0; j < 4; ++j) {
            const int idx = (m * 4 + n) * 4 + j;
            if (VBIT(idx)) {
              float x = acc[m][n][j];
              int b0e = (int)((x - mn) * sc0);
              b0e = b0e < 0 ? 0 : (b0e > 255 ? 255 : b0e);
              if (b0e == sb0) {
                int b1 = (int)((x - lo1) * sc1);
                b1 = b1 < 0 ? 0 : (b1 > 255 ? 255 : b1);
                atomicAdd(&hC[b1], 1u);
                atomicAdd(&hS[b1], x);
              }
            }
          }
      int sb2, R2, c2; float above2, bs2;
      if (largest) scanTopSum(hC, hS, lane, R0, sb2, R2, c2, above2, bs2);
      else         scanBotSum(hC, hS, lane, R0, sb2, R2, c2, above2, bs2);
      if (c2 <= 0) return binSum0 * ((float)R0 / (float)c0);
      return above2 + bs2 * ((float)R2 / (float)c2);
    };

    topS = sumA + refine(true, sbT, RT, cT, sBinT);
    botS = sumBlw + refine(false, sbB, RB, cB, sBinB);
  }
  #undef VBIT

  if (lane == 0) {
    float alpha = log1pf(expf(alpha_raw[0]));
    float beta = log1pf(expf(beta_raw[0]));
    float total_mean = tsum / (float)n_pair;
    float top_mean = topS / (float)ksel;
    float bm = fmaxf(0.0f, -(botS / (float)lsel));
    out[outIdx] = total_mean + alpha * top_mean - beta * bm;
  }
}

extern "C" void kernel_launch(void* const* d_in, const int* in_sizes, int n_in,
                              void* d_out, int out_size, void* d_ws, size_t ws_size,
                              hipStream_t stream) {
  (void)in_sizes; (void)n_in; (void)out_size;
  const float* q_emb = (const float*)d_in[0];
  const float* p_emb = (const float*)d_in[1];
  const void* q_mask = d_in[2];
  const void* p_mask = d_in[3];
  const float* alpha_raw = (const float*)d_in[4];
  const float* beta_raw = (const float*)d_in[5];
  float* out = (float*)d_out;

  const size_t needWs = ((size_t)(NA_G + NB_G)) * 16;  // 18.87 MB bf16 tiles
  if (ws_size >= needWs) {
    unsigned char* qt = (unsigned char*)d_ws;
    unsigned char* pt = qt + (size_t)NA_G * 16;
    hipLaunchKernelGGL(convert_pack, dim3((NA_G + NB_G) / 256), dim3(256), 0, stream,
                       q_emb, p_emb, qt, pt);
    hipLaunchKernelGGL((dpr_fused<1>), dim3(2048), dim3(TB), 0, stream,
                       q_emb, p_emb, q_mask, p_mask, alpha_raw, beta_raw, qt, pt, out);
  } else {
    hipLaunchKernelGGL((dpr_fused<0>), dim3(2048), dim3(TB), 0, stream,
                       q_emb, p_emb, q_mask, p_mask, alpha_raw, beta_raw,
                       (const unsigned char*)nullptr, (const unsigned char*)nullptr, out);
  }
}

// Round 7
// 153.463 us; speedup vs baseline: 1.8323x; 1.4993x over previous
//
#include <hip/hip_runtime.h>

#define TB 256
#define NA_G (32 * 12 * 1024)   // 16B-groups in A tiles
#define NB_G (64 * 12 * 1024)   // 16B-groups in B tiles
#define NEED_T ((size_t)(NA_G + NB_G) * 16)          // 18.87 MB bf16 tiles
#define NEED_S ((size_t)8192 * 4096 * 2)             // 67.1 MB bf16 S

typedef __bf16 bf16x8 __attribute__((ext_vector_type(8)));
typedef float f32x4 __attribute__((ext_vector_type(4)));
typedef unsigned short u16x8 __attribute__((ext_vector_type(8)));
typedef unsigned long long ull;

__device__ __forceinline__ unsigned pack2bf(float a, float b) {
  unsigned ua = __float_as_uint(a), ub = __float_as_uint(b);
  ua = (ua + 0x7fffu + ((ua >> 16) & 1u)) >> 16;   // RNE f32->bf16
  ub = (ub + 0x7fffu + ((ub >> 16) & 1u)) >> 16;
  return ua | (ub << 16);
}

// ascending-order 16-bit key for bf16 bits
__device__ __forceinline__ unsigned akey16(unsigned bits) {
  return (bits & 0x8000u) ? (bits ^ 0xFFFFu) : (bits | 0x8000u);
}
__device__ __forceinline__ float akey2f(unsigned ak) {
  unsigned bits = (ak & 0x8000u) ? (ak ^ 0x8000u) : (ak ^ 0xFFFFu);
  return __uint_as_float(bits << 16);
}
__device__ __forceinline__ float bf2f(unsigned bits) {
  return __uint_as_float(bits << 16);
}

// Pre-convert f32 -> bf16 into FRAGMENT-CONTIGUOUS 16KB tiles:
// tile t=(rb,kt): frag f=(rb2*2+ks), f*1024 + lane*16 holds
// src row rb*128+rb2*16+(lane&15), cols kt*64+ks*32+(lane>>4)*8..+8
__global__ __launch_bounds__(256) void convert_pack(
    const float* __restrict__ q, const float* __restrict__ p,
    unsigned char* __restrict__ qt, unsigned char* __restrict__ pt) {
  int g = blockIdx.x * 256 + threadIdx.x;
  const float* src;
  unsigned char* dst;
  if (g < NA_G) { src = q; dst = qt; }
  else { g -= NA_G; src = p; dst = pt; }
  int tile = g >> 10;
  int o = g & 1023;
  int f = o >> 6, l = o & 63;
  int rb2 = f >> 1, ks = f & 1;
  int lr = l & 15, lg = l >> 4;
  int rb = tile / 12, kt = tile - rb * 12;
  const float* s = src + (size_t)(rb * 128 + rb2 * 16 + lr) * 768 + kt * 64 + ks * 32 + lg * 8;
  float4 a = ((const float4*)s)[0];
  float4 b = ((const float4*)s)[1];
  uint4 w;
  w.x = pack2bf(a.x, a.y); w.y = pack2bf(a.z, a.w);
  w.z = pack2bf(b.x, b.y); w.w = pack2bf(b.z, b.w);
  *(uint4*)(dst + (size_t)tile * 16384 + (size_t)o * 16) = w;
}

// ================= split kernel 1: GEMM -> S (bf16) =================
template <int PATH>
__global__ __launch_bounds__(TB, 4) void dpr_gemm(
    const float* __restrict__ q_emb, const float* __restrict__ p_emb,
    const void* __restrict__ qmr, const void* __restrict__ pmr,
    const unsigned char* __restrict__ qt, const unsigned char* __restrict__ pt,
    unsigned short* __restrict__ Sout) {
  const int tid = threadIdx.x, lane = tid & 63, wid = tid >> 6;
  // XCD-clustered bid map: 8 regions of 16x16 tiles
  int g = blockIdx.x;
  int rg = g & 7, w = g >> 3;
  int blockB = (rg >> 2) * 16 + (w & 15);
  int blockP = (rg & 3) * 16 + (w >> 4);
  const int lr = lane & 15, lg = lane >> 4;
  const int db = wid >> 1, dp = wid & 1;

  // mask dtype sniff + per-wave masks (skip dead pairs)
  bool m32 = true;
  {
    const unsigned* qm32 = (const unsigned*)qmr;
    #pragma unroll
    for (int i = 0; i < 8; ++i) m32 = m32 && (qm32[i] <= 1u);
  }
  int qrow = (blockB * 2 + db) * 64 + lane;
  int pcolg = (blockP * 2 + dp) * 64 + lane;
  bool qvb = m32 ? (((const int*)qmr)[qrow] != 0) : (((const unsigned char*)qmr)[qrow] != 0);
  bool pvb = m32 ? (((const int*)pmr)[pcolg] != 0) : (((const unsigned char*)pmr)[pcolg] != 0);
  ull qb = __ballot(qvb);
  ull pb = __ballot(pvb);
  if (__popcll(qb) * __popcll(pb) == 0) return;   // selection writes -1e9

  f32x4 acc[4][4];
  #pragma unroll
  for (int m = 0; m < 4; ++m)
    #pragma unroll
    for (int n = 0; n < 4; ++n)
      acc[m][n] = f32x4{0.f, 0.f, 0.f, 0.f};

  if (PATH == 1) {
    const char* qbase = (const char*)qt + (((size_t)(blockB * 12)) << 14) + (db << 13) + lane * 16;
    const char* pbase = (const char*)pt + (((size_t)(blockP * 12)) << 14) + (dp << 13) + lane * 16;
    for (int kt = 0; kt < 12; ++kt) {
      #pragma unroll
      for (int ks = 0; ks < 2; ++ks) {
        const char* qa = qbase + (kt << 14) + (ks << 10);
        const char* pa = pbase + (kt << 14) + (ks << 10);
        bf16x8 af[4], bfr[4];
        #pragma unroll
        for (int m = 0; m < 4; ++m) af[m] = *(const bf16x8*)(qa + m * 2048);
        #pragma unroll
        for (int n = 0; n < 4; ++n) bfr[n] = *(const bf16x8*)(pa + n * 2048);
        #pragma unroll
        for (int m = 0; m < 4; ++m)
          #pragma unroll
          for (int n = 0; n < 4; ++n)
            acc[m][n] = __builtin_amdgcn_mfma_f32_16x16x32_bf16(af[m], bfr[n], acc[m][n], 0, 0, 0);
      }
    }
  } else {
    const float* qbase = q_emb + (size_t)(blockB * 128 + db * 64 + lr) * 768 + lg * 8;
    const float* pbase = p_emb + (size_t)(blockP * 128 + dp * 64 + lr) * 768 + lg * 8;
    for (int kt = 0; kt < 12; ++kt) {
      #pragma unroll
      for (int ks = 0; ks < 2; ++ks) {
        const int col = kt * 64 + ks * 32;
        bf16x8 af[4], bfr[4];
        #pragma unroll
        for (int m = 0; m < 4; ++m) {
          const float* s = qbase + (size_t)(m * 16) * 768 + col;
          float4 a = ((const float4*)s)[0], b = ((const float4*)s)[1];
          uint4 wv;
          wv.x = pack2bf(a.x, a.y); wv.y = pack2bf(a.z, a.w);
          wv.z = pack2bf(b.x, b.y); wv.w = pack2bf(b.z, b.w);
          af[m] = __builtin_bit_cast(bf16x8, wv);
        }
        #pragma unroll
        for (int n = 0; n < 4; ++n) {
          const float* s = pbase + (size_t)(n * 16) * 768 + col;
          float4 a = ((const float4*)s)[0], b = ((const float4*)s)[1];
          uint4 wv;
          wv.x = pack2bf(a.x, a.y); wv.y = pack2bf(a.z, a.w);
          wv.z = pack2bf(b.x, b.y); wv.w = pack2bf(b.z, b.w);
          bfr[n] = __builtin_bit_cast(bf16x8, wv);
        }
        #pragma unroll
        for (int m = 0; m < 4; ++m)
          #pragma unroll
          for (int n = 0; n < 4; ++n)
            acc[m][n] = __builtin_amdgcn_mfma_f32_16x16x32_bf16(af[m], bfr[n], acc[m][n], 0, 0, 0);
      }
    }
  }

  // epilogue: S[pair][c*64+r] bf16, c = n*16+lr (p-col), r = m*16+lg*4+j (q-row)
  const int pair = (blockB * 2 + db) * 128 + blockP * 2 + dp;
  unsigned short* Sp = Sout + ((size_t)pair << 12);
  #pragma unroll
  for (int m = 0; m < 4; ++m)
    #pragma unroll
    for (int n = 0; n < 4; ++n) {
      int so = (n * 16 + lr) * 64 + m * 16 + lg * 4;
      uint2 wv;
      wv.x = pack2bf(acc[m][n][0], acc[m][n][1]);
      wv.y = pack2bf(acc[m][n][2], acc[m][n][3]);
      *(uint2*)(Sp + so) = wv;
    }
}

// count-only rank scan over a 256-bin hist
__device__ __forceinline__ void scanC(const unsigned* h, int lane, int R,
                                      bool top, int& selB, int& Rin, int& cnt) {
  uint4 h4 = ((const uint4*)h)[lane];
  unsigned lsum = h4.x + h4.y + h4.z + h4.w;
  unsigned run = lsum;
  if (top) {
    #pragma unroll
    for (int off = 1; off < 64; off <<= 1) {
      unsigned o = __shfl_down(run, off);
      if (lane + off < 64) run += o;
    }
  } else {
    #pragma unroll
    for (int off = 1; off < 64; off <<= 1) {
      unsigned o = __shfl_up(run, off);
      if (lane >= off) run += o;
    }
  }
  unsigned excl = run - lsum;
  bool found = ((unsigned)R > excl) && ((unsigned)R <= run);
  int sb = 0, ri = 0, cc = 0;
  if (found) {
    unsigned a = excl;
    if (top) {
      if ((unsigned)R <= a + h4.w) { sb = 3; ri = R - (int)a; cc = (int)h4.w; }
      else { a += h4.w;
      if ((unsigned)R <= a + h4.z) { sb = 2; ri = R - (int)a; cc = (int)h4.z; }
      else { a += h4.z;
      if ((unsigned)R <= a + h4.y) { sb = 1; ri = R - (int)a; cc = (int)h4.y; }
      else { a += h4.y; sb = 0; ri = R - (int)a; cc = (int)h4.x; } } }
    } else {
      if ((unsigned)R <= a + h4.x) { sb = 0; ri = R - (int)a; cc = (int)h4.x; }
      else { a += h4.x;
      if ((unsigned)R <= a + h4.y) { sb = 1; ri = R - (int)a; cc = (int)h4.y; }
      else { a += h4.y;
      if ((unsigned)R <= a + h4.z) { sb = 2; ri = R - (int)a; cc = (int)h4.z; }
      else { a += h4.z; sb = 3; ri = R - (int)a; cc = (int)h4.w; } } }
    }
    sb += lane * 4;
  }
  ull fm = __ballot(found);
  int src = fm ? (int)__builtin_ctzll(fm) : 0;
  selB = __shfl(sb, src); Rin = __shfl(ri, src); cnt = __shfl(cc, src);
}

// ============== split kernel 2: radix selection over S ==============
__global__ __launch_bounds__(TB, 8) void dpr_select(
    const unsigned short* __restrict__ S,
    const void* __restrict__ qmr, const void* __restrict__ pmr,
    const float* __restrict__ alpha_raw, const float* __restrict__ beta_raw,
    float* __restrict__ out) {
  __shared__ unsigned harena[4][768];   // per wave: h1 | h2T | h2B
  const int tid = threadIdx.x, lane = tid & 63, wid = tid >> 6;
  const int pair = blockIdx.x * 4 + wid;
  const int b = pair >> 7, p = pair & 127;

  bool m32 = true;
  {
    const unsigned* qm32 = (const unsigned*)qmr;
    #pragma unroll
    for (int i = 0; i < 8; ++i) m32 = m32 && (qm32[i] <= 1u);
  }
  bool qvb = m32 ? (((const int*)qmr)[b * 64 + lane] != 0)
                 : (((const unsigned char*)qmr)[b * 64 + lane] != 0);
  bool pvb = m32 ? (((const int*)pmr)[p * 64 + lane] != 0)
                 : (((const unsigned char*)pmr)[p * 64 + lane] != 0);
  ull qb = __ballot(qvb);
  ull pb = __ballot(pvb);
  const int n_pair = __popcll(qb) * __popcll(pb);
  if (n_pair == 0) {
    if (lane == 0) out[pair] = -1e9f;
    return;
  }

  int ksel = 4 * n_pair / 10; if (ksel < 1) ksel = 1;
  int lsel = 2 * n_pair / 10; if (lsel < 1) lsel = 1;

  const unsigned short* Sp = S + ((size_t)pair << 12);
  const unsigned qm8 = (unsigned)((qb >> ((lane & 7) * 8)) & 0xFFull);
  unsigned* h1 = harena[wid];
  unsigned* h2T = harena[wid] + 256;
  unsigned* h2B = harena[wid] + 512;
  ((uint4*)h1)[lane] = uint4{0u, 0u, 0u, 0u};
  ((uint4*)h2T)[lane] = uint4{0u, 0u, 0u, 0u};
  ((uint4*)h2B)[lane] = uint4{0u, 0u, 0u, 0u};

  // pass 1: high-byte count hist + masked total sum
  float tsum = 0.f;
  #pragma unroll
  for (int t = 0; t < 8; ++t) {
    u16x8 v = *(const u16x8*)(Sp + t * 512 + lane * 8);
    unsigned pbit = (unsigned)((pb >> (t * 8 + (lane >> 3))) & 1ull);
    #pragma unroll
    for (int jj = 0; jj < 8; ++jj) {
      unsigned bits = (unsigned)v[jj];
      unsigned ak = akey16(bits);
      if (pbit & (qm8 >> jj) & 1u) {
        atomicAdd(&h1[ak >> 8], 1u);
        tsum += bf2f(bits);
      }
    }
  }
  #pragma unroll
  for (int off = 1; off < 64; off <<= 1) tsum += __shfl_xor(tsum, off);

  int sbT, RT, cT, sbB, RB, cB;
  scanC(h1, lane, ksel, true, sbT, RT, cT);
  scanC(h1, lane, lsel, false, sbB, RB, cB);

  // pass 2: low-byte sub-hists for the two rank bins
  #pragma unroll
  for (int t = 0; t < 8; ++t) {
    u16x8 v = *(const u16x8*)(Sp + t * 512 + lane * 8);
    unsigned pbit = (unsigned)((pb >> (t * 8 + (lane >> 3))) & 1ull);
    #pragma unroll
    for (int jj = 0; jj < 8; ++jj) {
      unsigned ak = akey16((unsigned)v[jj]);
      bool valid = (pbit & (qm8 >> jj) & 1u) != 0u;
      int hb = (int)(ak >> 8), lb = (int)(ak & 255u);
      if (valid && hb == sbT) atomicAdd(&h2T[lb], 1u);
      if (valid && hb == sbB) atomicAdd(&h2B[lb], 1u);
    }
  }
  int lT, r2T, c2T, lB, r2B, c2B;
  scanC(h2T, lane, RT, true, lT, r2T, c2T);
  scanC(h2B, lane, RB, false, lB, r2B, c2B);
  const unsigned akT = ((unsigned)sbT << 8) | (unsigned)lT;
  const unsigned akB = ((unsigned)sbB << 8) | (unsigned)lB;
  const float tT = akey2f(akT);
  const float tB = akey2f(akB);

  // pass 3: exact tie-aware sums vs exact bf16 thresholds
  float sT = 0.f, sB = 0.f;
  int cgt = 0, clt = 0;
  #pragma unroll
  for (int t = 0; t < 8; ++t) {
    u16x8 v = *(const u16x8*)(Sp + t * 512 + lane * 8);
    unsigned pbit = (unsigned)((pb >> (t * 8 + (lane >> 3))) & 1ull);
    #pragma unroll
    for (int jj = 0; jj < 8; ++jj) {
      unsigned bits = (unsigned)v[jj];
      unsigned ak = akey16(bits);
      if (pbit & (qm8 >> jj) & 1u) {
        float x = bf2f(bits);
        if (ak > akT) { sT += x; cgt++; }
        if (ak < akB) { sB += x; clt++; }
      }
    }
  }
  #pragma unroll
  for (int off = 1; off < 64; off <<= 1) {
    sT += __shfl_xor(sT, off);
    sB += __shfl_xor(sB, off);
    cgt += __shfl_xor(cgt, off);
    clt += __shfl_xor(clt, off);
  }

  if (lane == 0) {
    float top_sum = sT + tT * (float)(ksel - cgt);
    float bot_sum = sB + tB * (float)(lsel - clt);
    float alpha = log1pf(expf(alpha_raw[0]));
    float beta = log1pf(expf(beta_raw[0]));
    float total_mean = tsum / (float)n_pair;
    float top_mean = top_sum / (float)ksel;
    float bm = fmaxf(0.0f, -(bot_sum / (float)lsel));
    out[pair] = total_mean + alpha * top_mean - beta * bm;
  }
}

// ============== fallback: R6 fused kernel (ws too small) ==============
__device__ __forceinline__ void scanTopSum(const unsigned* hC, const float* hS,
                                           int lane, int R, int& selB, int& Rin,
                                           int& cnt, float& sumAbove, float& binSum) {
  uint4 c4 = ((const uint4*)hC)[lane];
  float4 s4 = ((const float4*)hS)[lane];
  unsigned lc = c4.x + c4.y + c4.z + c4.w;
  float ls = s4.x + s4.y + s4.z + s4.w;
  unsigned run = lc; float runv = ls;
  #pragma unroll
  for (int off = 1; off < 64; off <<= 1) {
    unsigned o = __shfl_down(run, off);
    float ov = __shfl_down(runv, off);
    if (lane + off < 64) { run += o; runv += ov; }
  }
  unsigned above = run - lc; float vabove = runv - ls;
  bool found = ((unsigned)R > above) && ((unsigned)R <= run);
  int sb = 0, ri = 0, cc = 0; float sa = 0.f, bs = 0.f;
  if (found) {
    unsigned a = above; float va = vabove;
    if ((unsigned)R <= a + c4.w) { sb = 3; ri = R - (int)a; cc = (int)c4.w; sa = va; bs = s4.w; }
    else { a += c4.w; va += s4.w;
    if ((unsigned)R <= a + c4.z) { sb = 2; ri = R - (int)a; cc = (int)c4.z; sa = va; bs = s4.z; }
    else { a += c4.z; va += s4.z;
    if ((unsigned)R <= a + c4.y) { sb = 1; ri = R - (int)a; cc = (int)c4.y; sa = va; bs = s4.y; }
    else { a += c4.y; va += s4.y; sb = 0; ri = R - (int)a; cc = (int)c4.x; sa = va; bs = s4.x; } } }
    sb += lane * 4;
  }
  ull fm = __ballot(found);
  int src = fm ? (int)__builtin_ctzll(fm) : 0;
  selB = __shfl(sb, src); Rin = __shfl(ri, src);
  cnt = __shfl(cc, src); sumAbove = __shfl(sa, src); binSum = __shfl(bs, src);
}

__device__ __forceinline__ void scanBotSum(const unsigned* hC, const float* hS,
                                           int lane, int R, int& selB, int& Rin,
                                           int& cnt, float& sumBelow, float& binSum) {
  uint4 c4 = ((const uint4*)hC)[lane];
  float4 s4 = ((const float4*)hS)[lane];
  unsigned lc = c4.x + c4.y + c4.z + c4.w;
  float ls = s4.x + s4.y + s4.z + s4.w;
  unsigned run = lc; float runv = ls;
  #pragma unroll
  for (int off = 1; off < 64; off <<= 1) {
    unsigned o = __shfl_up(run, off);
    float ov = __shfl_up(runv, off);
    if (lane >= off) { run += o; runv += ov; }
  }
  unsigned below = run - lc; float vbelow = runv - ls;
  bool found = ((unsigned)R > below) && ((unsigned)R <= run);
  int sb = 0, ri = 0, cc = 0; float sa = 0.f, bs = 0.f;
  if (found) {
    unsigned a = below; float va = vbelow;
    if ((unsigned)R <= a + c4.x) { sb = 0; ri = R - (int)a; cc = (int)c4.x; sa = va; bs = s4.x; }
    else { a += c4.x; va += s4.x;
    if ((unsigned)R <= a + c4.y) { sb = 1; ri = R - (int)a; cc = (int)c4.y; sa = va; bs = s4.y; }
    else { a += c4.y; va += s4.y;
    if ((unsigned)R <= a + c4.z) { sb = 2; ri = R - (int)a; cc = (int)c4.z; sa = va; bs = s4.z; }
    else { a += c4.z; va += s4.z; sb = 3; ri = R - (int)a; cc = (int)c4.w; sa = va; bs = s4.w; } } }
    sb += lane * 4;
  }
  ull fm = __ballot(found);
  int src = fm ? (int)__builtin_ctzll(fm) : 0;
  selB = __shfl(sb, src); Rin = __shfl(ri, src);
  cnt = __shfl(cc, src); sumBelow = __shfl(sa, src); binSum = __shfl(bs, src);
}

template <int PATH>
__global__ __launch_bounds__(TB, 4) void dpr_fused(
    const float* __restrict__ q_emb, const float* __restrict__ p_emb,
    const void* __restrict__ qmr, const void* __restrict__ pmr,
    const float* __restrict__ alpha_raw, const float* __restrict__ beta_raw,
    const unsigned char* __restrict__ qt, const unsigned char* __restrict__ pt,
    float* __restrict__ out) {
  __shared__ unsigned harena[4 * 512];
  const int tid = threadIdx.x, lane = tid & 63, wid = tid >> 6;
  const int bid = blockIdx.x, blockB = bid >> 6, blockP = bid & 63;
  const int lr = lane & 15, lg = lane >> 4;
  const int db = wid >> 1, dp = wid & 1;

  bool m32 = true;
  {
    const unsigned* qm32 = (const unsigned*)qmr;
    #pragma unroll
    for (int i = 0; i < 8; ++i) m32 = m32 && (qm32[i] <= 1u);
  }
  int qrow = (blockB * 2 + db) * 64 + lane;
  int pcolg = (blockP * 2 + dp) * 64 + lane;
  bool qvb = m32 ? (((const int*)qmr)[qrow] != 0) : (((const unsigned char*)qmr)[qrow] != 0);
  bool pvb = m32 ? (((const int*)pmr)[pcolg] != 0) : (((const unsigned char*)pmr)[pcolg] != 0);
  ull qb = __ballot(qvb);
  ull pb = __ballot(pvb);
  const int n_pair = __popcll(qb) * __popcll(pb);

  const int outIdx = (blockB * 2 + db) * 128 + (blockP * 2 + dp);
  if (n_pair == 0) {
    if (lane == 0) out[outIdx] = -1e9f;
    return;
  }

  f32x4 acc[4][4];
  #pragma unroll
  for (int m = 0; m < 4; ++m)
    #pragma unroll
    for (int n = 0; n < 4; ++n)
      acc[m][n] = f32x4{0.f, 0.f, 0.f, 0.f};

  if (PATH == 1) {
    const char* qbase = (const char*)qt + (((size_t)(blockB * 12)) << 14) + (db << 13) + lane * 16;
    const char* pbase = (const char*)pt + (((size_t)(blockP * 12)) << 14) + (dp << 13) + lane * 16;
    for (int kt = 0; kt < 12; ++kt) {
      #pragma unroll
      for (int ks = 0; ks < 2; ++ks) {
        const char* qa = qbase + (kt << 14) + (ks << 10);
        const char* pa = pbase + (kt << 14) + (ks << 10);
        bf16x8 af[4], bfr[4];
        #pragma unroll
        for (int m = 0; m < 4; ++m) af[m] = *(const bf16x8*)(qa + m * 2048);
        #pragma unroll
        for (int n = 0; n < 4; ++n) bfr[n] = *(const bf16x8*)(pa + n * 2048);
        #pragma unroll
        for (int m = 0; m < 4; ++m)
          #pragma unroll
          for (int n = 0; n < 4; ++n)
            acc[m][n] = __builtin_amdgcn_mfma_f32_16x16x32_bf16(af[m], bfr[n], acc[m][n], 0, 0, 0);
      }
    }
  } else {
    const float* qbase = q_emb + (size_t)(blockB * 128 + db * 64 + lr) * 768 + lg * 8;
    const float* pbase = p_emb + (size_t)(blockP * 128 + dp * 64 + lr) * 768 + lg * 8;
    for (int kt = 0; kt < 12; ++kt) {
      #pragma unroll
      for (int ks = 0; ks < 2; ++ks) {
        const int col = kt * 64 + ks * 32;
        bf16x8 af[4], bfr[4];
        #pragma unroll
        for (int m = 0; m < 4; ++m) {
          const float* s = qbase + (size_t)(m * 16) * 768 + col;
          float4 a = ((const float4*)s)[0], b2 = ((const float4*)s)[1];
          uint4 wv;
          wv.x = pack2bf(a.x, a.y); wv.y = pack2bf(a.z, a.w);
          wv.z = pack2bf(b2.x, b2.y); wv.w = pack2bf(b2.z, b2.w);
          af[m] = __builtin_bit_cast(bf16x8, wv);
        }
        #pragma unroll
        for (int n = 0; n < 4; ++n) {
          const float* s = pbase + (size_t)(n * 16) * 768 + col;
          float4 a = ((const float4*)s)[0], b2 = ((const float4*)s)[1];
          uint4 wv;
          wv.x = pack2bf(a.x, a.y); wv.y = pack2bf(a.z, a.w);
          wv.z = pack2bf(b2.x, b2.y); wv.w = pack2bf(b2.z, b2.w);
          bfr[n] = __builtin_bit_cast(bf16x8, wv);
        }
        #pragma unroll
        for (int m = 0; m < 4; ++m)
          #pragma unroll
          for (int n = 0; n < 4; ++n)
            acc[m][n] = __builtin_amdgcn_mfma_f32_16x16x32_bf16(af[m], bfr[n], acc[m][n], 0, 0, 0);
      }
    }
  }

  unsigned vlo = 0, vhi = 0;
  {
    unsigned qn[4], pc[4];
    #pragma unroll
    for (int m = 0; m < 4; ++m) qn[m] = (unsigned)((qb >> (m * 16 + lg * 4)) & 0xFull);
    #pragma unroll
    for (int n = 0; n < 4; ++n) pc[n] = ((pb >> (n * 16 + lr)) & 1ull) ? 0xFu : 0u;
    #pragma unroll
    for (int m = 0; m < 2; ++m)
      #pragma unroll
      for (int n = 0; n < 4; ++n) vlo |= (qn[m] & pc[n]) << ((m * 4 + n) * 4);
    #pragma unroll
    for (int m = 2; m < 4; ++m)
      #pragma unroll
      for (int n = 0; n < 4; ++n) vhi |= (qn[m] & pc[n]) << (((m - 2) * 4 + n) * 4);
  }
  #define VBIT(idx) ((idx) < 32 ? ((vlo >> (idx)) & 1u) : ((vhi >> ((idx) - 32)) & 1u))

  float tsum = 0.f, mn = INFINITY, mx = -INFINITY;
  #pragma unroll
  for (int m = 0; m < 4; ++m)
    #pragma unroll
    for (int n = 0; n < 4; ++n)
      #pragma unroll
      for (int j = 0; j < 4; ++j) {
        const int idx = (m * 4 + n) * 4 + j;
        float x = acc[m][n][j];
        if (VBIT(idx)) { tsum += x; mn = fminf(mn, x); mx = fmaxf(mx, x); }
      }
  #pragma unroll
  for (int off = 1; off < 64; off <<= 1) {
    tsum += __shfl_xor(tsum, off);
    mn = fminf(mn, __shfl_xor(mn, off));
    mx = fmaxf(mx, __shfl_xor(mx, off));
  }

  int ksel = 4 * n_pair / 10; if (ksel < 1) ksel = 1;
  int lsel = 2 * n_pair / 10; if (lsel < 1) lsel = 1;

  unsigned* hC = &harena[wid * 512];
  float* hS = (float*)&harena[wid * 512 + 256];

  float topS, botS;
  if (!(mx > mn)) {
    topS = (float)ksel * mn;
    botS = (float)lsel * mn;
  } else {
    const float w0 = (mx - mn) * (1.0f / 256.0f);
    const float sc0 = 1.0f / w0;
    ((uint4*)hC)[lane] = uint4{0u, 0u, 0u, 0u};
    ((float4*)hS)[lane] = float4{0.f, 0.f, 0.f, 0.f};
    #pragma unroll
    for (int m = 0; m < 4; ++m)
      #pragma unroll
      for (int n = 0; n < 4; ++n)
        #pragma unroll
        for (int j = 0; j < 4; ++j) {
          const int idx = (m * 4 + n) * 4 + j;
          if (VBIT(idx)) {
            float x = acc[m][n][j];
            int bn = (int)((x - mn) * sc0);
            bn = bn < 0 ? 0 : (bn > 255 ? 255 : bn);
            atomicAdd(&hC[bn], 1u);
            atomicAdd(&hS[bn], x);
          }
        }
    int sbT, RT, cT; float sumA, sBinT;
    int sbB, RB, cB; float sumBlw, sBinB;
    scanTopSum(hC, hS, lane, ksel, sbT, RT, cT, sumA, sBinT);
    scanBotSum(hC, hS, lane, lsel, sbB, RB, cB, sumBlw, sBinB);

    auto refine = [&](bool largest, int sb0, int R0, int c0, float binSum0) -> float {
      if (R0 >= c0) return binSum0;
      float lo1 = mn + w0 * (float)sb0;
      if (!(w0 > 0.f)) return binSum0 * ((float)R0 / (float)c0);
      ((uint4*)hC)[lane] = uint4{0u, 0u, 0u, 0u};
      ((float4*)hS)[lane] = float4{0.f, 0.f, 0.f, 0.f};
      const float sc1 = 256.0f / w0;
      #pragma unroll
      for (int m = 0; m < 4; ++m)
        #pragma unroll
        for (int n = 0; n < 4; ++n)
          #pragma unroll
          for (int j = 0; j < 4; ++j) {
            const int idx = (m * 4 + n) * 4 + j;
            if (VBIT(idx)) {
              float x = acc[m][n][j];
              int b0e = (int)((x - mn) * sc0);
              b0e = b0e < 0 ? 0 : (b0e > 255 ? 255 : b0e);
              if (b0e == sb0) {
                int b1 = (int)((x - lo1) * sc1);
                b1 = b1 < 0 ? 0 : (b1 > 255 ? 255 : b1);
                atomicAdd(&hC[b1], 1u);
                atomicAdd(&hS[b1], x);
              }
            }
          }
      int sb2, R2, c2; float above2, bs2;
      if (largest) scanTopSum(hC, hS, lane, R0, sb2, R2, c2, above2, bs2);
      else         scanBotSum(hC, hS, lane, R0, sb2, R2, c2, above2, bs2);
      if (c2 <= 0) return binSum0 * ((float)R0 / (float)c0);
      return above2 + bs2 * ((float)R2 / (float)c2);
    };

    topS = sumA + refine(true, sbT, RT, cT, sBinT);
    botS = sumBlw + refine(false, sbB, RB, cB, sBinB);
  }
  #undef VBIT

  if (lane == 0) {
    float alpha = log1pf(expf(alpha_raw[0]));
    float beta = log1pf(expf(beta_raw[0]));
    float total_mean = tsum / (float)n_pair;
    float top_mean = topS / (float)ksel;
    float bm = fmaxf(0.0f, -(botS / (float)lsel));
    out[outIdx] = total_mean + alpha * top_mean - beta * bm;
  }
}

extern "C" void kernel_launch(void* const* d_in, const int* in_sizes, int n_in,
                              void* d_out, int out_size, void* d_ws, size_t ws_size,
                              hipStream_t stream) {
  (void)in_sizes; (void)n_in; (void)out_size;
  const float* q_emb = (const float*)d_in[0];
  const float* p_emb = (const float*)d_in[1];
  const void* q_mask = d_in[2];
  const void* p_mask = d_in[3];
  const float* alpha_raw = (const float*)d_in[4];
  const float* beta_raw = (const float*)d_in[5];
  float* out = (float*)d_out;

  if (ws_size >= NEED_T + NEED_S) {
    unsigned char* qt = (unsigned char*)d_ws;
    unsigned char* pt = qt + (size_t)NA_G * 16;
    unsigned short* Sb = (unsigned short*)((unsigned char*)d_ws + NEED_T);
    hipLaunchKernelGGL(convert_pack, dim3((NA_G + NB_G) / 256), dim3(256), 0, stream,
                       q_emb, p_emb, qt, pt);
    hipLaunchKernelGGL((dpr_gemm<1>), dim3(2048), dim3(TB), 0, stream,
                       q_emb, p_emb, q_mask, p_mask, qt, pt, Sb);
    hipLaunchKernelGGL(dpr_select, dim3(2048), dim3(TB), 0, stream,
                       Sb, q_mask, p_mask, alpha_raw, beta_raw, out);
  } else if (ws_size >= NEED_S) {
    unsigned short* Sb = (unsigned short*)d_ws;
    hipLaunchKernelGGL((dpr_gemm<0>), dim3(2048), dim3(TB), 0, stream,
                       q_emb, p_emb, q_mask, p_mask,
                       (const unsigned char*)nullptr, (const unsigned char*)nullptr, Sb);
    hipLaunchKernelGGL(dpr_select, dim3(2048), dim3(TB), 0, stream,
                       Sb, q_mask, p_mask, alpha_raw, beta_raw, out);
  } else if (ws_size >= NEED_T) {
    unsigned char* qt = (unsigned char*)d_ws;
    unsigned char* pt = qt + (size_t)NA_G * 16;
    hipLaunchKernelGGL(convert_pack, dim3((NA_G + NB_G) / 256), dim3(256), 0, stream,
                       q_emb, p_emb, qt, pt);
    hipLaunchKernelGGL((dpr_fused<1>), dim3(2048), dim3(TB), 0, stream,
                       q_emb, p_emb, q_mask, p_mask, alpha_raw, beta_raw, qt, pt, out);
  } else {
    hipLaunchKernelGGL((dpr_fused<0>), dim3(2048), dim3(TB), 0, stream,
                       q_emb, p_emb, q_mask, p_mask, alpha_raw, beta_raw,
                       (const unsigned char*)nullptr, (const unsigned char*)nullptr, out);
  }
}

// Round 8
// 124.876 us; speedup vs baseline: 2.2517x; 1.2289x over previous
//
#include <hip/hip_runtime.h>

#define TB 256
#define NA_G (32 * 12 * 1024)   // 16B-groups in A tiles
#define NB_G (64 * 12 * 1024)   // 16B-groups in B tiles
#define NEED_T ((size_t)(NA_G + NB_G) * 16)          // 18.87 MB bf16 tiles
#define NEED_S ((size_t)8192 * 4096 * 2)             // 67.1 MB bf16 S

typedef __bf16 bf16x8 __attribute__((ext_vector_type(8)));
typedef float f32x4 __attribute__((ext_vector_type(4)));
typedef unsigned u32x4 __attribute__((ext_vector_type(4)));
typedef unsigned u32x2 __attribute__((ext_vector_type(2)));
typedef unsigned long long ull;

__device__ __forceinline__ unsigned pack2bf(float a, float b) {
  unsigned ua = __float_as_uint(a), ub = __float_as_uint(b);
  ua = (ua + 0x7fffu + ((ua >> 16) & 1u)) >> 16;   // RNE f32->bf16
  ub = (ub + 0x7fffu + ((ub >> 16) & 1u)) >> 16;
  return ua | (ub << 16);
}
__device__ __forceinline__ unsigned akey16(unsigned bits) {
  return (bits & 0x8000u) ? (bits ^ 0xFFFFu) : (bits | 0x8000u);
}
__device__ __forceinline__ float akey2f(unsigned ak) {
  unsigned bits = (ak & 0x8000u) ? (ak ^ 0x8000u) : (ak ^ 0xFFFFu);
  return __uint_as_float(bits << 16);
}
__device__ __forceinline__ float bf2f(unsigned bits) {
  return __uint_as_float(bits << 16);
}
__device__ __forceinline__ void gll16(const void* g, void* l) {
  __builtin_amdgcn_global_load_lds(
      (const __attribute__((address_space(1))) unsigned*)g,
      (__attribute__((address_space(3))) unsigned*)l, 16, 0, 0);
}

// Pre-convert f32 -> bf16 into XOR-swizzled 128x64 tiles (LDS-image layout, R5 format)
__global__ __launch_bounds__(256) void convert_pack(
    const float* __restrict__ q, const float* __restrict__ p,
    unsigned char* __restrict__ qt, unsigned char* __restrict__ pt) {
  int g = blockIdx.x * 256 + threadIdx.x;
  const float* src;
  unsigned char* dst;
  if (g < NA_G) { src = q; dst = qt; }
  else { g -= NA_G; src = p; dst = pt; }
  int tile = g >> 10;
  int o = (g & 1023) * 16;                 // byte offset in 16KB tile
  int row = o >> 7;
  int colb = (o & 127) ^ ((row & 7) << 4); // inverse of XOR swizzle
  int rb = tile / 12, kt = tile - rb * 12;
  const float* s = src + ((size_t)(rb * 128 + row)) * 768 + kt * 64 + (colb >> 1);
  float4 a = ((const float4*)s)[0];
  float4 b = ((const float4*)s)[1];
  uint4 w;
  w.x = pack2bf(a.x, a.y); w.y = pack2bf(a.z, a.w);
  w.z = pack2bf(b.x, b.y); w.w = pack2bf(b.z, b.w);
  *(uint4*)(dst + (size_t)tile * 16384 + o) = w;
}

// ========== kernel 1: LDS-staged GEMM -> S (bf16, coalesced NT stores) ==========
template <int PATH>
__global__ __launch_bounds__(TB, 4) void dpr_gemm(
    const float* __restrict__ q_emb, const float* __restrict__ p_emb,
    const unsigned char* __restrict__ qt, const unsigned char* __restrict__ pt,
    unsigned short* __restrict__ Sout) {
  __shared__ __align__(16) char arena[32768];   // GEMM: Al|Bl ; epilogue: 4x8KB S quadrants
  unsigned short* Al = (unsigned short*)arena;
  unsigned short* Bl = (unsigned short*)(arena + 16384);

  const int tid = threadIdx.x, lane = tid & 63, wid = tid >> 6;
  // XCD-clustered bid map: 8 regions of 16x16 block-tiles
  int g = blockIdx.x;
  int rg = g & 7, w = g >> 3;
  int blockB = (rg >> 2) * 16 + (w & 15);
  int blockP = (rg & 3) * 16 + (w >> 4);
  const int lr = lane & 15, lg = lane >> 4;
  const int db = wid >> 1, dp = wid & 1;

  f32x4 acc[4][4];
  #pragma unroll
  for (int m = 0; m < 4; ++m)
    #pragma unroll
    for (int n = 0; n < 4; ++n)
      acc[m][n] = f32x4{0.f, 0.f, 0.f, 0.f};

  const float* Abase = q_emb + (size_t)(blockB * 128) * 768;
  const float* Bbase = p_emb + (size_t)(blockP * 128) * 768;

  for (int kt = 0; kt < 12; ++kt) {
    if (PATH == 1) {
      const unsigned char* qtile = qt + ((size_t)(blockB * 12 + kt)) * 16384;
      const unsigned char* ptile = pt + ((size_t)(blockP * 12 + kt)) * 16384;
      #pragma unroll
      for (int c2 = 0; c2 < 4; ++c2) {
        int chunk = wid * 4 + c2;
        gll16(qtile + chunk * 1024 + lane * 16, (char*)Al + chunk * 1024);
        gll16(ptile + chunk * 1024 + lane * 16, (char*)Bl + chunk * 1024);
      }
    } else {
      const int k0 = kt * 64;
      #pragma unroll
      for (int it = 0; it < 4; ++it) {
        int gg = tid + 256 * it;
        int row = gg >> 3;
        int col = (gg & 7) * 8;
        int off = (row * 128 + col * 2) ^ ((row & 7) << 4);
        const float4* sA = (const float4*)(Abase + (size_t)row * 768 + k0 + col);
        float4 a0 = sA[0], a1 = sA[1];
        uint4 wv;
        wv.x = pack2bf(a0.x, a0.y); wv.y = pack2bf(a0.z, a0.w);
        wv.z = pack2bf(a1.x, a1.y); wv.w = pack2bf(a1.z, a1.w);
        *(uint4*)((char*)Al + off) = wv;
        const float4* sB = (const float4*)(Bbase + (size_t)row * 768 + k0 + col);
        float4 b0 = sB[0], b1 = sB[1];
        wv.x = pack2bf(b0.x, b0.y); wv.y = pack2bf(b0.z, b0.w);
        wv.z = pack2bf(b1.x, b1.y); wv.w = pack2bf(b1.z, b1.w);
        *(uint4*)((char*)Bl + off) = wv;
      }
    }
    __syncthreads();
    #pragma unroll
    for (int ks = 0; ks < 2; ++ks) {
      bf16x8 af[4], bfr[4];
      #pragma unroll
      for (int m = 0; m < 4; ++m) {
        int row = db * 64 + m * 16 + lr;
        int off = (row * 128 + ks * 64 + lg * 16) ^ ((row & 7) << 4);
        af[m] = *(const bf16x8*)((const char*)Al + off);
      }
      #pragma unroll
      for (int n = 0; n < 4; ++n) {
        int row = dp * 64 + n * 16 + lr;
        int off = (row * 128 + ks * 64 + lg * 16) ^ ((row & 7) << 4);
        bfr[n] = *(const bf16x8*)((const char*)Bl + off);
      }
      #pragma unroll
      for (int m = 0; m < 4; ++m)
        #pragma unroll
        for (int n = 0; n < 4; ++n)
          acc[m][n] = __builtin_amdgcn_mfma_f32_16x16x32_bf16(af[m], bfr[n], acc[m][n], 0, 0, 0);
    }
    __syncthreads();   // last one also fences arena reuse by epilogue
  }

  // epilogue: stage S quadrant in LDS (XOR-swizzled), stream out coalesced NT.
  // layout: S[pair][c*64 + r], c = n*16+lr (p-col), r = m*16+lg*4+j (q-row)
  char* Sq = arena + wid * 8192;
  #pragma unroll
  for (int m = 0; m < 4; ++m)
    #pragma unroll
    for (int n = 0; n < 4; ++n) {
      int row = n * 16 + lr;
      int byte = row * 128 + m * 32 + lg * 8;
      int swz = byte ^ ((row & 7) << 4);
      u32x2 wv;
      wv.x = pack2bf(acc[m][n][0], acc[m][n][1]);
      wv.y = pack2bf(acc[m][n][2], acc[m][n][3]);
      *(u32x2*)(Sq + swz) = wv;
    }
  // same-wave readback (in-order LDS), no barrier needed
  const int pair = (blockB * 2 + db) * 128 + blockP * 2 + dp;
  unsigned short* Sp = Sout + ((size_t)pair << 12);
  #pragma unroll
  for (int i = 0; i < 8; ++i) {
    int base = i * 1024 + lane * 16;
    int swz = base ^ ((lane >> 3) << 4);
    u32x4 v = *(const u32x4*)(Sq + swz);
    __builtin_nontemporal_store(v, (u32x4*)((char*)Sp + base));
  }
}

// count-only rank scan over a 256-bin hist
__device__ __forceinline__ void scanC(const unsigned* h, int lane, int R,
                                      bool top, int& selB, int& Rin, int& cnt) {
  uint4 h4 = ((const uint4*)h)[lane];
  unsigned lsum = h4.x + h4.y + h4.z + h4.w;
  unsigned run = lsum;
  if (top) {
    #pragma unroll
    for (int off = 1; off < 64; off <<= 1) {
      unsigned o = __shfl_down(run, off);
      if (lane + off < 64) run += o;
    }
  } else {
    #pragma unroll
    for (int off = 1; off < 64; off <<= 1) {
      unsigned o = __shfl_up(run, off);
      if (lane >= off) run += o;
    }
  }
  unsigned excl = run - lsum;
  bool found = ((unsigned)R > excl) && ((unsigned)R <= run);
  int sb = 0, ri = 0, cc = 0;
  if (found) {
    unsigned a = excl;
    if (top) {
      if ((unsigned)R <= a + h4.w) { sb = 3; ri = R - (int)a; cc = (int)h4.w; }
      else { a += h4.w;
      if ((unsigned)R <= a + h4.z) { sb = 2; ri = R - (int)a; cc = (int)h4.z; }
      else { a += h4.z;
      if ((unsigned)R <= a + h4.y) { sb = 1; ri = R - (int)a; cc = (int)h4.y; }
      else { a += h4.y; sb = 0; ri = R - (int)a; cc = (int)h4.x; } } }
    } else {
      if ((unsigned)R <= a + h4.x) { sb = 0; ri = R - (int)a; cc = (int)h4.x; }
      else { a += h4.x;
      if ((unsigned)R <= a + h4.y) { sb = 1; ri = R - (int)a; cc = (int)h4.y; }
      else { a += h4.y;
      if ((unsigned)R <= a + h4.z) { sb = 2; ri = R - (int)a; cc = (int)h4.z; }
      else { a += h4.z; sb = 3; ri = R - (int)a; cc = (int)h4.w; } } }
    }
    sb += lane * 4;
  }
  ull fm = __ballot(found);
  int src = fm ? (int)__builtin_ctzll(fm) : 0;
  selB = __shfl(sb, src); Rin = __shfl(ri, src); cnt = __shfl(cc, src);
}

// ========== kernel 2: single-pass register-cached radix selection ==========
__global__ __launch_bounds__(TB, 6) void dpr_select(
    const unsigned short* __restrict__ S,
    const void* __restrict__ qmr, const void* __restrict__ pmr,
    const float* __restrict__ alpha_raw, const float* __restrict__ beta_raw,
    float* __restrict__ out) {
  __shared__ unsigned harena[4][768];   // per wave: h1 | h2T | h2B
  const int tid = threadIdx.x, lane = tid & 63, wid = tid >> 6;
  const int pair = blockIdx.x * 4 + wid;
  const int b = pair >> 7, p = pair & 127;

  bool m32 = true;
  {
    const unsigned* qm32 = (const unsigned*)qmr;
    #pragma unroll
    for (int i = 0; i < 8; ++i) m32 = m32 && (qm32[i] <= 1u);
  }
  bool qvb = m32 ? (((const int*)qmr)[b * 64 + lane] != 0)
                 : (((const unsigned char*)qmr)[b * 64 + lane] != 0);
  bool pvb = m32 ? (((const int*)pmr)[p * 64 + lane] != 0)
                 : (((const unsigned char*)pmr)[p * 64 + lane] != 0);
  ull qb = __ballot(qvb);
  ull pb = __ballot(pvb);
  const int n_pair = __popcll(qb) * __popcll(pb);
  if (n_pair == 0) {
    if (lane == 0) out[pair] = -1e9f;
    return;
  }

  int ksel = 4 * n_pair / 10; if (ksel < 1) ksel = 1;
  int lsel = 2 * n_pair / 10; if (lsel < 1) lsel = 1;

  // load this pair's 64 values / lane ONCE into registers (32 VGPRs)
  const unsigned short* Sp = S + ((size_t)pair << 12);
  u32x4 vv[8];
  #pragma unroll
  for (int t = 0; t < 8; ++t)
    vv[t] = __builtin_nontemporal_load((const u32x4*)(Sp + t * 512 + lane * 8));

  const unsigned qm8 = (unsigned)((qb >> ((lane & 7) * 8)) & 0xFFull);
  unsigned pm8 = 0;
  #pragma unroll
  for (int t = 0; t < 8; ++t)
    pm8 |= (unsigned)((pb >> (t * 8 + (lane >> 3))) & 1ull) << t;

  unsigned* h1 = harena[wid];
  unsigned* h2T = harena[wid] + 256;
  unsigned* h2B = harena[wid] + 512;
  ((uint4*)h1)[lane] = uint4{0u, 0u, 0u, 0u};
  ((uint4*)h2T)[lane] = uint4{0u, 0u, 0u, 0u};
  ((uint4*)h2B)[lane] = uint4{0u, 0u, 0u, 0u};

  // pass 1 (regs): high-byte count hist + masked total sum
  float tsum = 0.f;
  #pragma unroll
  for (int t = 0; t < 8; ++t) {
    if ((pm8 >> t) & 1u) {
      #pragma unroll
      for (int jj = 0; jj < 8; ++jj) {
        unsigned u = vv[t][jj >> 1];
        unsigned bits = (jj & 1) ? (u >> 16) : (u & 0xFFFFu);
        if ((qm8 >> jj) & 1u) {
          atomicAdd(&h1[akey16(bits) >> 8], 1u);
          tsum += bf2f(bits);
        }
      }
    }
  }
  #pragma unroll
  for (int off = 1; off < 64; off <<= 1) tsum += __shfl_xor(tsum, off);

  int sbT, RT, cT, sbB, RB, cB;
  scanC(h1, lane, ksel, true, sbT, RT, cT);
  scanC(h1, lane, lsel, false, sbB, RB, cB);

  // pass 2 (regs): low-byte sub-hists for the two rank bins
  #pragma unroll
  for (int t = 0; t < 8; ++t) {
    if ((pm8 >> t) & 1u) {
      #pragma unroll
      for (int jj = 0; jj < 8; ++jj) {
        unsigned u = vv[t][jj >> 1];
        unsigned bits = (jj & 1) ? (u >> 16) : (u & 0xFFFFu);
        if ((qm8 >> jj) & 1u) {
          unsigned ak = akey16(bits);
          int hb = (int)(ak >> 8), lb = (int)(ak & 255u);
          if (hb == sbT) atomicAdd(&h2T[lb], 1u);
          if (hb == sbB) atomicAdd(&h2B[lb], 1u);
        }
      }
    }
  }
  int lT, r2T, c2T, lB, r2B, c2B;
  scanC(h2T, lane, RT, true, lT, r2T, c2T);
  scanC(h2B, lane, RB, false, lB, r2B, c2B);
  const unsigned akT = ((unsigned)sbT << 8) | (unsigned)lT;
  const unsigned akB = ((unsigned)sbB << 8) | (unsigned)lB;
  const float tT = akey2f(akT);
  const float tB = akey2f(akB);

  // pass 3 (regs): exact tie-aware sums vs exact bf16 thresholds
  float sT = 0.f, sB = 0.f;
  int cgt = 0, clt = 0;
  #pragma unroll
  for (int t = 0; t < 8; ++t) {
    if ((pm8 >> t) & 1u) {
      #pragma unroll
      for (int jj = 0; jj < 8; ++jj) {
        unsigned u = vv[t][jj >> 1];
        unsigned bits = (jj & 1) ? (u >> 16) : (u & 0xFFFFu);
        if ((qm8 >> jj) & 1u) {
          unsigned ak = akey16(bits);
          float x = bf2f(bits);
          if (ak > akT) { sT += x; cgt++; }
          if (ak < akB) { sB += x; clt++; }
        }
      }
    }
  }
  #pragma unroll
  for (int off = 1; off < 64; off <<= 1) {
    sT += __shfl_xor(sT, off);
    sB += __shfl_xor(sB, off);
    cgt += __shfl_xor(cgt, off);
    clt += __shfl_xor(clt, off);
  }

  if (lane == 0) {
    float top_sum = sT + tT * (float)(ksel - cgt);
    float bot_sum = sB + tB * (float)(lsel - clt);
    float alpha = log1pf(expf(alpha_raw[0]));
    float beta = log1pf(expf(beta_raw[0]));
    float total_mean = tsum / (float)n_pair;
    float top_mean = top_sum / (float)ksel;
    float bm = fmaxf(0.0f, -(bot_sum / (float)lsel));
    out[pair] = total_mean + alpha * top_mean - beta * bm;
  }
}

// ========== last-resort fused fallback (no workspace): R5 structure ==========
__device__ __forceinline__ void scanTopSum(const unsigned* hC, const float* hS,
                                           int lane, int R, int& selB, int& Rin,
                                           int& cnt, float& sumAbove, float& binSum) {
  uint4 c4 = ((const uint4*)hC)[lane];
  float4 s4 = ((const float4*)hS)[lane];
  unsigned lc = c4.x + c4.y + c4.z + c4.w;
  float ls = s4.x + s4.y + s4.z + s4.w;
  unsigned run = lc; float runv = ls;
  #pragma unroll
  for (int off = 1; off < 64; off <<= 1) {
    unsigned o = __shfl_down(run, off);
    float ov = __shfl_down(runv, off);
    if (lane + off < 64) { run += o; runv += ov; }
  }
  unsigned above = run - lc; float vabove = runv - ls;
  bool found = ((unsigned)R > above) && ((unsigned)R <= run);
  int sb = 0, ri = 0, cc = 0; float sa = 0.f, bs = 0.f;
  if (found) {
    unsigned a = above; float va = vabove;
    if ((unsigned)R <= a + c4.w) { sb = 3; ri = R - (int)a; cc = (int)c4.w; sa = va; bs = s4.w; }
    else { a += c4.w; va += s4.w;
    if ((unsigned)R <= a + c4.z) { sb = 2; ri = R - (int)a; cc = (int)c4.z; sa = va; bs = s4.z; }
    else { a += c4.z; va += s4.z;
    if ((unsigned)R <= a + c4.y) { sb = 1; ri = R - (int)a; cc = (int)c4.y; sa = va; bs = s4.y; }
    else { a += c4.y; va += s4.y; sb = 0; ri = R - (int)a; cc = (int)c4.x; sa = va; bs = s4.x; } } }
    sb += lane * 4;
  }
  ull fm = __ballot(found);
  int src = fm ? (int)__builtin_ctzll(fm) : 0;
  selB = __shfl(sb, src); Rin = __shfl(ri, src);
  cnt = __shfl(cc, src); sumAbove = __shfl(sa, src); binSum = __shfl(bs, src);
}

__device__ __forceinline__ void scanBotSum(const unsigned* hC, const float* hS,
                                           int lane, int R, int& selB, int& Rin,
                                           int& cnt, float& sumBelow, float& binSum) {
  uint4 c4 = ((const uint4*)hC)[lane];
  float4 s4 = ((const float4*)hS)[lane];
  unsigned lc = c4.x + c4.y + c4.z + c4.w;
  float ls = s4.x + s4.y + s4.z + s4.w;
  unsigned run = lc; float runv = ls;
  #pragma unroll
  for (int off = 1; off < 64; off <<= 1) {
    unsigned o = __shfl_up(run, off);
    float ov = __shfl_up(runv, off);
    if (lane >= off) { run += o; runv += ov; }
  }
  unsigned below = run - lc; float vbelow = runv - ls;
  bool found = ((unsigned)R > below) && ((unsigned)R <= run);
  int sb = 0, ri = 0, cc = 0; float sa = 0.f, bs = 0.f;
  if (found) {
    unsigned a = below; float va = vbelow;
    if ((unsigned)R <= a + c4.x) { sb = 0; ri = R - (int)a; cc = (int)c4.x; sa = va; bs = s4.x; }
    else { a += c4.x; va += s4.x;
    if ((unsigned)R <= a + c4.y) { sb = 1; ri = R - (int)a; cc = (int)c4.y; sa = va; bs = s4.y; }
    else { a += c4.y; va += s4.y;
    if ((unsigned)R <= a + c4.z) { sb = 2; ri = R - (int)a; cc = (int)c4.z; sa = va; bs = s4.z; }
    else { a += c4.z; va += s4.z; sb = 3; ri = R - (int)a; cc = (int)c4.w; sa = va; bs = s4.w; } } }
    sb += lane * 4;
  }
  ull fm = __ballot(found);
  int src = fm ? (int)__builtin_ctzll(fm) : 0;
  selB = __shfl(sb, src); Rin = __shfl(ri, src);
  cnt = __shfl(cc, src); sumBelow = __shfl(sa, src); binSum = __shfl(bs, src);
}

__global__ __launch_bounds__(TB, 3) void dpr_fused0(
    const float* __restrict__ q_emb, const float* __restrict__ p_emb,
    const void* __restrict__ qmr, const void* __restrict__ pmr,
    const float* __restrict__ alpha_raw, const float* __restrict__ beta_raw,
    float* __restrict__ out) {
  __shared__ __align__(16) char arena[32768];
  unsigned short* Al = (unsigned short*)arena;
  unsigned short* Bl = (unsigned short*)(arena + 16384);
  const int tid = threadIdx.x, lane = tid & 63, wid = tid >> 6;
  const int bid = blockIdx.x, blockB = bid >> 6, blockP = bid & 63;
  const int lr = lane & 15, lg = lane >> 4;
  const int db = wid >> 1, dp = wid & 1;

  bool m32 = true;
  {
    const unsigned* qm32 = (const unsigned*)qmr;
    #pragma unroll
    for (int i = 0; i < 8; ++i) m32 = m32 && (qm32[i] <= 1u);
  }
  int qrow = (blockB * 2 + db) * 64 + lane;
  int pcolg = (blockP * 2 + dp) * 64 + lane;
  bool qvb = m32 ? (((const int*)qmr)[qrow] != 0) : (((const unsigned char*)qmr)[qrow] != 0);
  bool pvb = m32 ? (((const int*)pmr)[pcolg] != 0) : (((const unsigned char*)pmr)[pcolg] != 0);
  ull qb = __ballot(qvb);
  ull pb = __ballot(pvb);
  const int n_pair = __popcll(qb) * __popcll(pb);

  f32x4 acc[4][4];
  #pragma unroll
  for (int m = 0; m < 4; ++m)
    #pragma unroll
    for (int n = 0; n < 4; ++n)
      acc[m][n] = f32x4{0.f, 0.f, 0.f, 0.f};

  const float* Abase = q_emb + (size_t)(blockB * 128) * 768;
  const float* Bbase = p_emb + (size_t)(blockP * 128) * 768;

  for (int kt = 0; kt < 12; ++kt) {
    const int k0 = kt * 64;
    #pragma unroll
    for (int it = 0; it < 4; ++it) {
      int gg = tid + 256 * it;
      int row = gg >> 3;
      int col = (gg & 7) * 8;
      int off = (row * 128 + col * 2) ^ ((row & 7) << 4);
      const float4* sA = (const float4*)(Abase + (size_t)row * 768 + k0 + col);
      float4 a0 = sA[0], a1 = sA[1];
      uint4 wv;
      wv.x = pack2bf(a0.x, a0.y); wv.y = pack2bf(a0.z, a0.w);
      wv.z = pack2bf(a1.x, a1.y); wv.w = pack2bf(a1.z, a1.w);
      *(uint4*)((char*)Al + off) = wv;
      const float4* sB = (const float4*)(Bbase + (size_t)row * 768 + k0 + col);
      float4 b0 = sB[0], b1 = sB[1];
      wv.x = pack2bf(b0.x, b0.y); wv.y = pack2bf(b0.z, b0.w);
      wv.z = pack2bf(b1.x, b1.y); wv.w = pack2bf(b1.z, b1.w);
      *(uint4*)((char*)Bl + off) = wv;
    }
    __syncthreads();
    #pragma unroll
    for (int ks = 0; ks < 2; ++ks) {
      bf16x8 af[4], bfr[4];
      #pragma unroll
      for (int m = 0; m < 4; ++m) {
        int row = db * 64 + m * 16 + lr;
        int off = (row * 128 + ks * 64 + lg * 16) ^ ((row & 7) << 4);
        af[m] = *(const bf16x8*)((const char*)Al + off);
      }
      #pragma unroll
      for (int n = 0; n < 4; ++n) {
        int row = dp * 64 + n * 16 + lr;
        int off = (row * 128 + ks * 64 + lg * 16) ^ ((row & 7) << 4);
        bfr[n] = *(const bf16x8*)((const char*)Bl + off);
      }
      #pragma unroll
      for (int m = 0; m < 4; ++m)
        #pragma unroll
        for (int n = 0; n < 4; ++n)
          acc[m][n] = __builtin_amdgcn_mfma_f32_16x16x32_bf16(af[m], bfr[n], acc[m][n], 0, 0, 0);
    }
    __syncthreads();
  }

  const int outIdx = (blockB * 2 + db) * 128 + (blockP * 2 + dp);
  if (n_pair == 0) {
    if (lane == 0) out[outIdx] = -1e9f;
    return;
  }

  unsigned vlo = 0, vhi = 0;
  {
    unsigned qn[4], pc[4];
    #pragma unroll
    for (int m = 0; m < 4; ++m) qn[m] = (unsigned)((qb >> (m * 16 + lg * 4)) & 0xFull);
    #pragma unroll
    for (int n = 0; n < 4; ++n) pc[n] = ((pb >> (n * 16 + lr)) & 1ull) ? 0xFu : 0u;
    #pragma unroll
    for (int m = 0; m < 2; ++m)
      #pragma unroll
      for (int n = 0; n < 4; ++n) vlo |= (qn[m] & pc[n]) << ((m * 4 + n) * 4);
    #pragma unroll
    for (int m = 2; m < 4; ++m)
      #pragma unroll
      for (int n = 0; n < 4; ++n) vhi |= (qn[m] & pc[n]) << (((m - 2) * 4 + n) * 4);
  }
  #define VBIT(idx) ((idx) < 32 ? ((vlo >> (idx)) & 1u) : ((vhi >> ((idx) - 32)) & 1u))

  float tsum = 0.f, mn = INFINITY, mx = -INFINITY;
  #pragma unroll
  for (int m = 0; m < 4; ++m)
    #pragma unroll
    for (int n = 0; n < 4; ++n)
      #pragma unroll
      for (int j = 0; j < 4; ++j) {
        const int idx = (m * 4 + n) * 4 + j;
        float x = acc[m][n][j];
        if (VBIT(idx)) { tsum += x; mn = fminf(mn, x); mx = fmaxf(mx, x); }
      }
  #pragma unroll
  for (int off = 1; off < 64; off <<= 1) {
    tsum += __shfl_xor(tsum, off);
    mn = fminf(mn, __shfl_xor(mn, off));
    mx = fmaxf(mx, __shfl_xor(mx, off));
  }

  int ksel = 4 * n_pair / 10; if (ksel < 1) ksel = 1;
  int lsel = 2 * n_pair / 10; if (lsel < 1) lsel = 1;

  unsigned* hC = (unsigned*)(arena + wid * 2048);
  float* hS = (float*)(arena + wid * 2048 + 1024);

  float topS, botS;
  if (!(mx > mn)) {
    topS = (float)ksel * mn;
    botS = (float)lsel * mn;
  } else {
    const float w0 = (mx - mn) * (1.0f / 256.0f);
    const float sc0 = 1.0f / w0;
    ((uint4*)hC)[lane] = uint4{0u, 0u, 0u, 0u};
    ((float4*)hS)[lane] = float4{0.f, 0.f, 0.f, 0.f};
    #pragma unroll
    for (int m = 0; m < 4; ++m)
      #pragma unroll
      for (int n = 0; n < 4; ++n)
        #pragma unroll
        for (int j = 0; j < 4; ++j) {
          const int idx = (m * 4 + n) * 4 + j;
          if (VBIT(idx)) {
            float x = acc[m][n][j];
            int bn = (int)((x - mn) * sc0);
            bn = bn < 0 ? 0 : (bn > 255 ? 255 : bn);
            atomicAdd(&hC[bn], 1u);
            atomicAdd(&hS[bn], x);
          }
        }
    int sbT, RT, cT; float sumA, sBinT;
    int sbB, RB, cB; float sumBlw, sBinB;
    scanTopSum(hC, hS, lane, ksel, sbT, RT, cT, sumA, sBinT);
    scanBotSum(hC, hS, lane, lsel, sbB, RB, cB, sumBlw, sBinB);

    auto refine = [&](bool largest, int sb0, int R0, int c0, float binSum0) -> float {
      if (R0 >= c0) return binSum0;
      float lo1 = mn + w0 * (float)sb0;
      if (!(w0 > 0.f)) return binSum0 * ((float)R0 / (float)c0);
      ((uint4*)hC)[lane] = uint4{0u, 0u, 0u, 0u};
      ((float4*)hS)[lane] = float4{0.f, 0.f, 0.f, 0.f};
      const float sc1 = 256.0f / w0;
      #pragma unroll
      for (int m = 0; m < 4; ++m)
        #pragma unroll
        for (int n = 0; n < 4; ++n)
          #pragma unroll
          for (int j = 0; j < 4; ++j) {
            const int idx = (m * 4 + n) * 4 + j;
            if (VBIT(idx)) {
              float x = acc[m][n][j];
              int b0e = (int)((x - mn) * sc0);
              b0e = b0e < 0 ? 0 : (b0e > 255 ? 255 : b0e);
              if (b0e == sb0) {
                int b1 = (int)((x - lo1) * sc1);
                b1 = b1 < 0 ? 0 : (b1 > 255 ? 255 : b1);
                atomicAdd(&hC[b1], 1u);
                atomicAdd(&hS[b1], x);
              }
            }
          }
      int sb2, R2, c2; float above2, bs2;
      if (largest) scanTopSum(hC, hS, lane, R0, sb2, R2, c2, above2, bs2);
      else         scanBotSum(hC, hS, lane, R0, sb2, R2, c2, above2, bs2);
      if (c2 <= 0) return binSum0 * ((float)R0 / (float)c0);
      return above2 + bs2 * ((float)R2 / (float)c2);
    };

    topS = sumA + refine(true, sbT, RT, cT, sBinT);
    botS = sumBlw + refine(false, sbB, RB, cB, sBinB);
  }
  #undef VBIT

  if (lane == 0) {
    float alpha = log1pf(expf(alpha_raw[0]));
    float beta = log1pf(expf(beta_raw[0]));
    float total_mean = tsum / (float)n_pair;
    float top_mean = topS / (float)ksel;
    float bm = fmaxf(0.0f, -(botS / (float)lsel));
    out[outIdx] = total_mean + alpha * top_mean - beta * bm;
  }
}

extern "C" void kernel_launch(void* const* d_in, const int* in_sizes, int n_in,
                              void* d_out, int out_size, void* d_ws, size_t ws_size,
                              hipStream_t stream) {
  (void)in_sizes; (void)n_in; (void)out_size;
  const float* q_emb = (const float*)d_in[0];
  const float* p_emb = (const float*)d_in[1];
  const void* q_mask = d_in[2];
  const void* p_mask = d_in[3];
  const float* alpha_raw = (const float*)d_in[4];
  const float* beta_raw = (const float*)d_in[5];
  float* out = (float*)d_out;

  if (ws_size >= NEED_T + NEED_S) {
    unsigned char* qt = (unsigned char*)d_ws;
    unsigned char* pt = qt + (size_t)NA_G * 16;
    unsigned short* Sb = (unsigned short*)((unsigned char*)d_ws + NEED_T);
    hipLaunchKernelGGL(convert_pack, dim3((NA_G + NB_G) / 256), dim3(256), 0, stream,
                       q_emb, p_emb, qt, pt);
    hipLaunchKernelGGL((dpr_gemm<1>), dim3(2048), dim3(TB), 0, stream,
                       q_emb, p_emb, qt, pt, Sb);
    hipLaunchKernelGGL(dpr_select, dim3(2048), dim3(TB), 0, stream,
                       Sb, q_mask, p_mask, alpha_raw, beta_raw, out);
  } else if (ws_size >= NEED_S) {
    unsigned short* Sb = (unsigned short*)d_ws;
    hipLaunchKernelGGL((dpr_gemm<0>), dim3(2048), dim3(TB), 0, stream,
                       q_emb, p_emb,
                       (const unsigned char*)nullptr, (const unsigned char*)nullptr, Sb);
    hipLaunchKernelGGL(dpr_select, dim3(2048), dim3(TB), 0, stream,
                       Sb, q_mask, p_mask, alpha_raw, beta_raw, out);
  } else {
    hipLaunchKernelGGL(dpr_fused0, dim3(2048), dim3(TB), 0, stream,
                       q_emb, p_emb, q_mask, p_mask, alpha_raw, beta_raw, out);
  }
}